// Round 3
// baseline (943.274 us; speedup 1.0000x reference)
//
#include <hip/hip_runtime.h>

#define NN   100000
#define TL   128
#define OC   5
#define KW   7
#define ST   3
#define CL   41          // (128-7)/3+1
#define FLAT 205         // 5*41
#define EMB  32
#define HID  16
#define NE   3200000

#define CNODES 128               // nodes per bucket
#define NBUCK  782               // ceil(NN/128)
#define NPAD   8192              // bucket capacity (2x mean of 4096, +64 sigma)
#define TILE   8192              // edges per k_bin block
#define NBIN   391               // ceil(NE/TILE)

// ===========================================================================
// Precompute combined weight Wc = g1w1 @ fc_w  ([16 x 205], j-major wcT) and
// bc = g1w1 @ fc_b.  Also init per-bucket bin cursors gcur[b] = b*NPAD.
// ===========================================================================
__global__ __launch_bounds__(256) void k_prep(
    const float* __restrict__ g1w1, const float* __restrict__ fc_w,
    const float* __restrict__ fc_b,
    float* __restrict__ wcT, float* __restrict__ bc,
    int* __restrict__ gcur)
{
    int tid = threadIdx.x;
    for (int idx = tid; idx < FLAT * HID; idx += 256) {
        int l = idx & 15;
        int j = idx >> 4;
        float s = 0.f;
        #pragma unroll
        for (int m = 0; m < EMB; ++m)
            s = fmaf(g1w1[l * EMB + m], fc_w[m * FLAT + j], s);
        wcT[j * HID + l] = s;
    }
    if (tid < HID) {
        float s = 0.f;
        #pragma unroll
        for (int m = 0; m < EMB; ++m)
            s = fmaf(g1w1[tid * EMB + m], fc_b[m], s);
        bc[tid] = s;
    }
    for (int b = tid; b < NBUCK; b += 256)
        gcur[b] = b * NPAD;
}

// ===========================================================================
// Fused Conv1d+ReLU+FC(+g1w1): 32-node tile per block (unchanged, verified).
// ===========================================================================
__global__ __launch_bounds__(256) void k_convfc(
    const float* __restrict__ x,
    const float* __restrict__ conv_w, const float* __restrict__ conv_b,
    const float* __restrict__ wcT,   const float* __restrict__ bc,
    float* __restrict__ p1)
{
    __shared__ float s_x[32 * 129];
    __shared__ float s_h[FLAT * 32];
    const int tid = threadIdx.x;
    const long long n0 = (long long)blockIdx.x * 32;   // NN = 32*3125 exact

    const float4* xv = (const float4*)(x + n0 * TL);
    #pragma unroll
    for (int c = 0; c < 4; ++c) {
        int f4  = c * 256 + tid;
        int row = f4 >> 5;
        int c4  = f4 & 31;
        float4 v = xv[f4];
        float* d = s_x + row * 129 + c4 * 4;
        d[0] = v.x; d[1] = v.y; d[2] = v.z; d[3] = v.w;
    }
    __syncthreads();

    for (int idx = tid; idx < FLAT * 32; idx += 256) {
        int n = idx & 31;
        int o = idx >> 5;
        int c = o / CL;
        int t = o - c * CL;
        float acc = conv_b[c];
        const float* wr = conv_w + c * KW;
        const float* xr = s_x + n * 129 + t * ST;
        #pragma unroll
        for (int k = 0; k < KW; ++k)
            acc = fmaf(xr[k], wr[k], acc);
        s_h[o * 32 + n] = fmaxf(acc, 0.f);
    }
    __syncthreads();

    const int l  = tid & 15;
    const int n2 = tid >> 4;
    float a0 = bc[l];
    float a1 = a0;
    #pragma unroll 5
    for (int j = 0; j < FLAT; ++j) {
        float w = wcT[j * HID + l];
        a0 = fmaf(s_h[j * 32 + n2],      w, a0);
        a1 = fmaf(s_h[j * 32 + n2 + 16], w, a1);
    }
    p1[(n0 + n2)      * HID + l] = a0;
    p1[(n0 + n2 + 16) * HID + l] = a1;
}

// ===========================================================================
// LDS-staged bucket binning.  Per 8192-edge tile: LDS histogram over 782
// buckets (dst>>7) -> one atomic reservation per (block,bucket) -> LDS
// scatter of packed (local_dst<<17)|src -> coalesced run copy to global.
// Eliminates the 170 MB of partial-line HBM writeback the counting-sort
// fill suffered (scattered 4B stores -> ~64B writeback each).
// ===========================================================================
__global__ __launch_bounds__(256) void k_bin(
    const int* __restrict__ ei, int* __restrict__ gcur,
    unsigned int* __restrict__ gbin)
{
    __shared__ unsigned int s_stage[TILE];
    __shared__ int s_cnt[NBUCK], s_ofs[NBUCK], s_base[NBUCK], s_loc[NBUCK];
    __shared__ int s_sum[256];

    const int tid = threadIdx.x;
    const int e0  = blockIdx.x * TILE;
    const int cntE = min(TILE, NE - e0);

    for (int b = tid; b < NBUCK; b += 256) s_cnt[b] = 0;
    __syncthreads();

    // P1: histogram
    for (int i = tid; i < cntE; i += 256) {
        int d = ei[NE + e0 + i];
        atomicAdd(&s_cnt[d >> 7], 1);
    }
    __syncthreads();

    // P2a: global reservation (one atomic per nonempty bucket per block)
    for (int b = tid; b < NBUCK; b += 256)
        s_base[b] = atomicAdd(&gcur[b], s_cnt[b]);

    // P2b: exclusive scan of s_cnt -> s_ofs (256 chunks of 4)
    int v0 = 0, v1 = 0, v2 = 0, v3 = 0;
    {
        int i0 = tid * 4;
        if (i0 + 0 < NBUCK) v0 = s_cnt[i0 + 0];
        if (i0 + 1 < NBUCK) v1 = s_cnt[i0 + 1];
        if (i0 + 2 < NBUCK) v2 = s_cnt[i0 + 2];
        if (i0 + 3 < NBUCK) v3 = s_cnt[i0 + 3];
    }
    int csum = v0 + v1 + v2 + v3;
    s_sum[tid] = csum;
    __syncthreads();
    #pragma unroll
    for (int d = 1; d < 256; d <<= 1) {
        int t = (tid >= d) ? s_sum[tid - d] : 0;
        __syncthreads();
        s_sum[tid] += t;
        __syncthreads();
    }
    {
        int run = s_sum[tid] - csum;
        int i0 = tid * 4;
        if (i0 + 0 < NBUCK) { s_ofs[i0 + 0] = run; run += v0; }
        if (i0 + 1 < NBUCK) { s_ofs[i0 + 1] = run; run += v1; }
        if (i0 + 2 < NBUCK) { s_ofs[i0 + 2] = run; run += v2; }
        if (i0 + 3 < NBUCK) { s_ofs[i0 + 3] = run; run += v3; }
    }
    __syncthreads();
    for (int b = tid; b < NBUCK; b += 256) s_loc[b] = s_ofs[b];
    __syncthreads();

    // P3: scatter packed words into LDS staging
    for (int i = tid; i < cntE; i += 256) {
        int s = ei[e0 + i];
        int d = ei[NE + e0 + i];
        int b = d >> 7;
        int pos = atomicAdd(&s_loc[b], 1);
        s_stage[pos] = ((unsigned int)(d & 127) << 17) | (unsigned int)s;
    }
    __syncthreads();

    // P4: coalesced run copy-out (wave per bucket)
    const int wid = tid >> 6, lane = tid & 63;
    for (int b = wid; b < NBUCK; b += 4) {
        int cnt = s_cnt[b];
        if (!cnt) continue;
        int gb  = s_base[b];
        int lim = min(cnt, b * NPAD + NPAD - gb);   // overflow clamp (never hits)
        int so  = s_ofs[b];
        for (int j = lane; j < lim; j += 64)
            gbin[(size_t)gb + j] = s_stage[so + j];
    }
}

// ===========================================================================
// Fused gather-aggregate + GIN MLP.  One block per 128-node bucket:
//   quad-per-edge: read packed run (coalesced), gather feat[src] (float4/lane,
//   L3-resident), accumulate into LDS (pad 17 -> low-conflict ds_add_f32,
//   conflict-free readback), then per-node MLP epilogue in-block.
// ===========================================================================
__global__ __launch_bounds__(256) void k_gagg1(
    const float* __restrict__ feat, const unsigned int* __restrict__ gbin,
    const int* __restrict__ gcur,
    const float* __restrict__ b1, const float* __restrict__ w2,
    const float* __restrict__ b2, const float* __restrict__ w3,
    float* __restrict__ outfeat)
{
    __shared__ float s_acc[CNODES * 17];
    __shared__ float s_w2[HID * HID], s_w3[HID * HID], s_b1[HID], s_b2[HID];
    const int tid = threadIdx.x;
    const int b   = blockIdx.x;

    s_w2[tid] = w2[tid];
    s_w3[tid] = w3[tid];
    if (tid < HID) { s_b1[tid] = b1[tid]; s_b2[tid] = b2[tid]; }
    for (int i = tid; i < CNODES * 17; i += 256) s_acc[i] = 0.f;
    __syncthreads();

    const int cnt = min(gcur[b] - b * NPAD, NPAD);
    const unsigned int* run = gbin + (size_t)b * NPAD;
    const float4* pv = (const float4*)feat;
    const int q = tid & 3;
    for (int i = tid >> 2; i < cnt; i += 64) {
        unsigned int w = run[i];
        int src = (int)(w & 0x1FFFFu);
        int ld  = (int)(w >> 17);
        float4 v = pv[(size_t)src * 4 + q];
        float* a = s_acc + ld * 17 + q * 4;
        atomicAdd(a + 0, v.x); atomicAdd(a + 1, v.y);
        atomicAdd(a + 2, v.z); atomicAdd(a + 3, v.w);
    }
    __syncthreads();

    const int node = b * CNODES + tid;
    if (tid < CNODES && node < NN) {
        const float4* fr = (const float4*)(feat + (size_t)node * HID);
        float t[HID];
        #pragma unroll
        for (int i = 0; i < 4; ++i) {
            float4 f = fr[i];
            t[i*4+0] = fmaxf(f.x + s_acc[tid*17 + i*4+0] + s_b1[i*4+0], 0.f);
            t[i*4+1] = fmaxf(f.y + s_acc[tid*17 + i*4+1] + s_b1[i*4+1], 0.f);
            t[i*4+2] = fmaxf(f.z + s_acc[tid*17 + i*4+2] + s_b1[i*4+2], 0.f);
            t[i*4+3] = fmaxf(f.w + s_acc[tid*17 + i*4+3] + s_b1[i*4+3], 0.f);
        }
        float h[HID];
        #pragma unroll
        for (int i = 0; i < HID; ++i) {
            float acc = s_b2[i];
            #pragma unroll
            for (int j = 0; j < HID; ++j) acc += t[j] * s_w2[i * HID + j];
            h[i] = fmaxf(acc, 0.f);
        }
        float o[HID];
        #pragma unroll
        for (int i = 0; i < HID; ++i) {
            float acc = 0.f;
            #pragma unroll
            for (int j = 0; j < HID; ++j) acc += h[j] * s_w3[i * HID + j];
            o[i] = acc;
        }
        float4* po = (float4*)(outfeat + (size_t)node * HID);
        #pragma unroll
        for (int i = 0; i < 4; ++i)
            po[i] = make_float4(o[i*4+0], o[i*4+1], o[i*4+2], o[i*4+3]);
    }
}

__global__ __launch_bounds__(256) void k_gagg2(
    const float* __restrict__ feat, const unsigned int* __restrict__ gbin,
    const int* __restrict__ gcur,
    const float* __restrict__ b1, const float* __restrict__ w2,
    const float* __restrict__ b2, const float* __restrict__ row,
    const float* __restrict__ rob,
    float* __restrict__ out)
{
    __shared__ float s_acc[CNODES * 17];
    __shared__ float s_w2[HID * HID], s_b1[HID], s_b2[HID], s_ro[HID];
    const int tid = threadIdx.x;
    const int b   = blockIdx.x;

    s_w2[tid] = w2[tid];
    if (tid < HID) { s_b1[tid] = b1[tid]; s_b2[tid] = b2[tid]; s_ro[tid] = row[tid]; }
    for (int i = tid; i < CNODES * 17; i += 256) s_acc[i] = 0.f;
    __syncthreads();

    const int cnt = min(gcur[b] - b * NPAD, NPAD);
    const unsigned int* run = gbin + (size_t)b * NPAD;
    const float4* pv = (const float4*)feat;
    const int q = tid & 3;
    for (int i = tid >> 2; i < cnt; i += 64) {
        unsigned int w = run[i];
        int src = (int)(w & 0x1FFFFu);
        int ld  = (int)(w >> 17);
        float4 v = pv[(size_t)src * 4 + q];
        float* a = s_acc + ld * 17 + q * 4;
        atomicAdd(a + 0, v.x); atomicAdd(a + 1, v.y);
        atomicAdd(a + 2, v.z); atomicAdd(a + 3, v.w);
    }
    __syncthreads();

    const int node = b * CNODES + tid;
    if (tid < CNODES && node < NN) {
        const float4* fr = (const float4*)(feat + (size_t)node * HID);
        float t[HID];
        #pragma unroll
        for (int i = 0; i < 4; ++i) {
            float4 f = fr[i];
            t[i*4+0] = fmaxf(f.x + s_acc[tid*17 + i*4+0] + s_b1[i*4+0], 0.f);
            t[i*4+1] = fmaxf(f.y + s_acc[tid*17 + i*4+1] + s_b1[i*4+1], 0.f);
            t[i*4+2] = fmaxf(f.z + s_acc[tid*17 + i*4+2] + s_b1[i*4+2], 0.f);
            t[i*4+3] = fmaxf(f.w + s_acc[tid*17 + i*4+3] + s_b1[i*4+3], 0.f);
        }
        float res = rob[0];
        #pragma unroll
        for (int i = 0; i < HID; ++i) {
            float acc = s_b2[i];
            #pragma unroll
            for (int j = 0; j < HID; ++j) acc += t[j] * s_w2[i * HID + j];
            res += fmaxf(acc, 0.f) == acc || true ? acc * 0.f : 0.f; // placeholder no-op (removed below)
            res -= 0.f;
            res += acc * s_ro[i];
        }
        out[node] = res;
    }
}

// ===========================================================================
// FALLBACK PATH kernels (workspace too small): per-node embed + atomic scatter
// ===========================================================================
__global__ __launch_bounds__(256) void k_embed(
    const float* __restrict__ x,
    const float* __restrict__ conv_w, const float* __restrict__ conv_b,
    const float* __restrict__ fc_w,   const float* __restrict__ fc_b,
    const float* __restrict__ g1w1,
    float* __restrict__ p1)
{
    __shared__ float s_x[4][TL];
    __shared__ float s_h[4][FLAT + 3];
    __shared__ float s_e[4][EMB];

    const int w    = threadIdx.x >> 6;
    const int lane = threadIdx.x & 63;
    const int node = blockIdx.x * 4 + w;

    const float2* xr = (const float2*)(x + (size_t)node * TL);
    float2 v = xr[lane];
    s_x[w][lane * 2 + 0] = v.x;
    s_x[w][lane * 2 + 1] = v.y;
    __syncthreads();

    for (int o = lane; o < FLAT; o += 64) {
        int c = o / CL;
        int t = o - c * CL;
        float acc = conv_b[c];
        #pragma unroll
        for (int k = 0; k < KW; ++k)
            acc += s_x[w][t * ST + k] * conv_w[c * KW + k];
        s_h[w][o] = fmaxf(acc, 0.f);
    }
    __syncthreads();

    if (lane < EMB) {
        float acc = fc_b[lane];
        const float* wr = fc_w + lane * FLAT;
        for (int j = 0; j < FLAT; ++j)
            acc += s_h[w][j] * wr[j];
        s_e[w][lane] = acc;
    }
    __syncthreads();

    if (lane < HID) {
        float acc = 0.f;
        const float* wr = g1w1 + lane * EMB;
        #pragma unroll
        for (int j = 0; j < EMB; ++j)
            acc += s_e[w][j] * wr[j];
        p1[(size_t)node * HID + lane] = acc;
    }
}

__global__ __launch_bounds__(256) void k_scatter(
    const float* __restrict__ p, const int* __restrict__ ei,
    float* __restrict__ agg)
{
    long long t = (long long)blockIdx.x * 256 + threadIdx.x;
    int e = (int)(t >> 4);
    int k = (int)(t & 15);
    if (e >= NE) return;
    int src = ei[e];
    int dst = ei[NE + e];
    float v = p[(size_t)src * HID + k];
    atomicAdd(agg + (size_t)dst * HID + k, v);
}

__global__ __launch_bounds__(256) void k_mlp1(
    const float* __restrict__ p1, const float* __restrict__ agg,
    const float* __restrict__ b1, const float* __restrict__ w2,
    const float* __restrict__ b2, const float* __restrict__ w3,
    float* __restrict__ p2)
{
    __shared__ float s_w2[HID * HID], s_w3[HID * HID], s_b1[HID], s_b2[HID];
    int tid = threadIdx.x;
    s_w2[tid] = w2[tid];
    s_w3[tid] = w3[tid];
    if (tid < HID) { s_b1[tid] = b1[tid]; s_b2[tid] = b2[tid]; }
    __syncthreads();

    int n = blockIdx.x * 256 + tid;
    if (n >= NN) return;

    float t[HID], h[HID];
    const float4* pa = (const float4*)(p1  + (size_t)n * HID);
    const float4* pb = (const float4*)(agg + (size_t)n * HID);
    #pragma unroll
    for (int i = 0; i < 4; ++i) {
        float4 a = pa[i], b = pb[i];
        t[i*4+0] = fmaxf(a.x + b.x + s_b1[i*4+0], 0.f);
        t[i*4+1] = fmaxf(a.y + b.y + s_b1[i*4+1], 0.f);
        t[i*4+2] = fmaxf(a.z + b.z + s_b1[i*4+2], 0.f);
        t[i*4+3] = fmaxf(a.w + b.w + s_b1[i*4+3], 0.f);
    }
    #pragma unroll
    for (int i = 0; i < HID; ++i) {
        float acc = s_b2[i];
        #pragma unroll
        for (int j = 0; j < HID; ++j) acc += t[j] * s_w2[i * HID + j];
        h[i] = fmaxf(acc, 0.f);
    }
    float o[HID];
    #pragma unroll
    for (int i = 0; i < HID; ++i) {
        float acc = 0.f;
        #pragma unroll
        for (int j = 0; j < HID; ++j) acc += h[j] * s_w3[i * HID + j];
        o[i] = acc;
    }
    float4* po = (float4*)(p2 + (size_t)n * HID);
    #pragma unroll
    for (int i = 0; i < 4; ++i)
        po[i] = make_float4(o[i*4+0], o[i*4+1], o[i*4+2], o[i*4+3]);
}

__global__ __launch_bounds__(256) void k_final(
    const float* __restrict__ p2, const float* __restrict__ agg2,
    const float* __restrict__ b1, const float* __restrict__ w2,
    const float* __restrict__ b2, const float* __restrict__ row,
    const float* __restrict__ rob,
    float* __restrict__ out)
{
    __shared__ float s_w2[HID * HID], s_b1[HID], s_b2[HID], s_ro[HID];
    int tid = threadIdx.x;
    s_w2[tid] = w2[tid];
    if (tid < HID) { s_b1[tid] = b1[tid]; s_b2[tid] = b2[tid]; s_ro[tid] = row[tid]; }
    __syncthreads();

    int n = blockIdx.x * 256 + tid;
    if (n >= NN) return;

    float t[HID];
    const float4* pa = (const float4*)(p2   + (size_t)n * HID);
    const float4* pb = (const float4*)(agg2 + (size_t)n * HID);
    #pragma unroll
    for (int i = 0; i < 4; ++i) {
        float4 a = pa[i], b = pb[i];
        t[i*4+0] = fmaxf(a.x + b.x + s_b1[i*4+0], 0.f);
        t[i*4+1] = fmaxf(a.y + b.y + s_b1[i*4+1], 0.f);
        t[i*4+2] = fmaxf(a.z + b.z + s_b1[i*4+2], 0.f);
        t[i*4+3] = fmaxf(a.w + b.w + s_b1[i*4+3], 0.f);
    }
    float res = rob[0];
    #pragma unroll
    for (int i = 0; i < HID; ++i) {
        float acc = s_b2[i];
        #pragma unroll
        for (int j = 0; j < HID; ++j) acc += t[j] * s_w2[i * HID + j];
        res += acc * s_ro[i];
    }
    out[n] = res;
}

// ===========================================================================
extern "C" void kernel_launch(void* const* d_in, const int* in_sizes, int n_in,
                              void* d_out, int out_size, void* d_ws, size_t ws_size,
                              hipStream_t stream)
{
    const float* x      = (const float*)d_in[0];
    const int*   ei     = (const int*)  d_in[1];
    const float* conv_w = (const float*)d_in[2];
    const float* conv_b = (const float*)d_in[3];
    const float* fc_w   = (const float*)d_in[4];
    const float* fc_b   = (const float*)d_in[5];
    const float* g1w1   = (const float*)d_in[6];
    const float* g1b1   = (const float*)d_in[7];
    const float* g1w2   = (const float*)d_in[8];
    const float* g1b2   = (const float*)d_in[9];
    const float* g2w1   = (const float*)d_in[10];
    const float* g2b1   = (const float*)d_in[11];
    const float* g2w2   = (const float*)d_in[12];
    const float* g2b2   = (const float*)d_in[13];
    const float* ro_w   = (const float*)d_in[14];
    const float* ro_b   = (const float*)d_in[15];
    float* out = (float*)d_out;

    // workspace layout:
    //   A    [NN*HID] f32       p1 (projected features)
    //   B    [NN*HID] f32       p2 (layer-2 projected features)
    //   wcT  [FLAT*HID] f32     combined fc+g1w1 weight
    //   bc   [16] f32           combined bias
    //   gcur [NBUCK] i32        bucket cursors
    //   bin  [NBUCK*NPAD] u32   packed (local_dst<<17)|src, bucketed by dst>>7
    float* A    = (float*)d_ws;
    float* B    = A + (size_t)NN * HID;
    float* wcT  = B + (size_t)NN * HID;
    float* bc   = wcT + (size_t)FLAT * HID;
    int*   gcur = (int*)(bc + 16);
    unsigned int* bin = (unsigned int*)(gcur + NBUCK);
    const size_t need = (size_t)((char*)(bin + (size_t)NBUCK * NPAD) - (char*)d_ws);

    if (ws_size >= need) {
        k_prep<<<1, 256, 0, stream>>>(g1w1, fc_w, fc_b, wcT, bc, gcur);
        k_convfc<<<NN / 32, 256, 0, stream>>>(x, conv_w, conv_b, wcT, bc, A);
        k_bin<<<NBIN, 256, 0, stream>>>(ei, gcur, bin);
        // GIN layer 1: fused gather-aggregate + MLP + layer-2 projection
        k_gagg1<<<NBUCK, 256, 0, stream>>>(A, bin, gcur, g1b1, g1w2, g1b2,
                                           g2w1, B);
        // GIN layer 2: fused gather-aggregate + MLP + readout
        k_gagg2<<<NBUCK, 256, 0, stream>>>(B, bin, gcur, g2b1, g2w2, g2b2,
                                           ro_w, ro_b, out);
    } else {
        // --- fallback: fused per-node embed + atomic scatter ---
        k_embed<<<NN / 4, 256, 0, stream>>>(x, conv_w, conv_b, fc_w, fc_b,
                                            g1w1, A);
        hipMemsetAsync(B, 0, (size_t)NN * HID * sizeof(float), stream);
        k_scatter<<<(int)(((long long)NE * HID) / 256), 256, 0, stream>>>(A, ei, B);
        k_mlp1<<<(NN + 255) / 256, 256, 0, stream>>>(A, B, g1b1, g1w2, g1b2,
                                                     g2w1, A);
        hipMemsetAsync(B, 0, (size_t)NN * HID * sizeof(float), stream);
        k_scatter<<<(int)(((long long)NE * HID) / 256), 256, 0, stream>>>(A, ei, B);
        k_final<<<(NN + 255) / 256, 256, 0, stream>>>(A, B, g2b1, g2w2, g2b2,
                                                      ro_w, ro_b, out);
    }
}

// Round 4
// 927.563 us; speedup vs baseline: 1.0169x; 1.0169x over previous
//
#include <hip/hip_runtime.h>

#define NN   100000
#define TL   128
#define OC   5
#define KW   7
#define ST   3
#define CL   41          // (128-7)/3+1
#define FLAT 205         // 5*41
#define EMB  32
#define HID  16
#define NE   3200000

#define CNODES 64                // nodes per bucket (dst>>6)
#define NBUCK  1563              // ceil(NN/64)
#define NPAD   8192              // bucket capacity in slots (mean fill ~3300)
#define TILE   16384             // edges per k_bin block
#define NBIN   196               // ceil(NE/TILE)
#define SENT   0xFFFFFFFFu       // sentinel slot (real words are < 2^23)

// ===========================================================================
// Precompute combined weight Wc = g1w1 @ fc_w  ([16 x 205], j-major wcT) and
// bc = g1w1 @ fc_b.  Also init per-bucket bin cursors gcur[b] = b*NPAD.
// ===========================================================================
__global__ __launch_bounds__(256) void k_prep(
    const float* __restrict__ g1w1, const float* __restrict__ fc_w,
    const float* __restrict__ fc_b,
    float* __restrict__ wcT, float* __restrict__ bc,
    int* __restrict__ gcur)
{
    int tid = threadIdx.x;
    for (int idx = tid; idx < FLAT * HID; idx += 256) {
        int l = idx & 15;
        int j = idx >> 4;
        float s = 0.f;
        #pragma unroll
        for (int m = 0; m < EMB; ++m)
            s = fmaf(g1w1[l * EMB + m], fc_w[m * FLAT + j], s);
        wcT[j * HID + l] = s;
    }
    if (tid < HID) {
        float s = 0.f;
        #pragma unroll
        for (int m = 0; m < EMB; ++m)
            s = fmaf(g1w1[tid * EMB + m], fc_b[m], s);
        bc[tid] = s;
    }
    for (int b = tid; b < NBUCK; b += 256)
        gcur[b] = b * NPAD;
}

// ===========================================================================
// Fused Conv1d+ReLU+FC(+g1w1): 32-node tile per block (unchanged, verified).
// ===========================================================================
__global__ __launch_bounds__(256) void k_convfc(
    const float* __restrict__ x,
    const float* __restrict__ conv_w, const float* __restrict__ conv_b,
    const float* __restrict__ wcT,   const float* __restrict__ bc,
    float* __restrict__ p1)
{
    __shared__ float s_x[32 * 129];
    __shared__ float s_h[FLAT * 32];
    const int tid = threadIdx.x;
    const long long n0 = (long long)blockIdx.x * 32;   // NN = 32*3125 exact

    const float4* xv = (const float4*)(x + n0 * TL);
    #pragma unroll
    for (int c = 0; c < 4; ++c) {
        int f4  = c * 256 + tid;
        int row = f4 >> 5;
        int c4  = f4 & 31;
        float4 v = xv[f4];
        float* d = s_x + row * 129 + c4 * 4;
        d[0] = v.x; d[1] = v.y; d[2] = v.z; d[3] = v.w;
    }
    __syncthreads();

    for (int idx = tid; idx < FLAT * 32; idx += 256) {
        int n = idx & 31;
        int o = idx >> 5;
        int c = o / CL;
        int t = o - c * CL;
        float acc = conv_b[c];
        const float* wr = conv_w + c * KW;
        const float* xr = s_x + n * 129 + t * ST;
        #pragma unroll
        for (int k = 0; k < KW; ++k)
            acc = fmaf(xr[k], wr[k], acc);
        s_h[o * 32 + n] = fmaxf(acc, 0.f);
    }
    __syncthreads();

    const int l  = tid & 15;
    const int n2 = tid >> 4;
    float a0 = bc[l];
    float a1 = a0;
    #pragma unroll 5
    for (int j = 0; j < FLAT; ++j) {
        float w = wcT[j * HID + l];
        a0 = fmaf(s_h[j * 32 + n2],      w, a0);
        a1 = fmaf(s_h[j * 32 + n2 + 16], w, a1);
    }
    p1[(n0 + n2)      * HID + l] = a0;
    p1[(n0 + n2 + 16) * HID + l] = a1;
}

// ===========================================================================
// LDS-staged bucket binning, line-exclusive output chunks.
// Per 16384-edge tile: LDS histogram over 1563 buckets (dst>>6) -> one
// 16-word-ALIGNED reservation per (block,bucket) (so every 64B line in gbin
// has exactly ONE writing block -> no cross-XCD partial-line writeback) ->
// LDS scatter of packed (local_dst<<17)|src -> coalesced run copy-out,
// sentinel-padded to the aligned reservation.
// LDS: stage 64KB + 3*6.2KB + 1KB = ~84KB -> 1 block/CU.
// ===========================================================================
__global__ __launch_bounds__(256) void k_bin(
    const int* __restrict__ ei, int* __restrict__ gcur,
    unsigned int* __restrict__ gbin)
{
    __shared__ unsigned int s_stage[TILE];
    __shared__ int s_cnt[NBUCK], s_ofs[NBUCK], s_base[NBUCK];
    __shared__ int s_sum[256];

    const int tid = threadIdx.x;
    const int e0  = blockIdx.x * TILE;
    const int cntE = min(TILE, NE - e0);

    for (int b = tid; b < NBUCK; b += 256) s_cnt[b] = 0;
    __syncthreads();

    // P1: histogram
    for (int i = tid; i < cntE; i += 256)
        atomicAdd(&s_cnt[ei[NE + e0 + i] >> 6], 1);
    __syncthreads();

    // P2a: aligned global reservation (one atomic per nonempty bucket)
    for (int b = tid; b < NBUCK; b += 256) {
        int c = s_cnt[b];
        s_base[b] = c ? atomicAdd(&gcur[b], (c + 15) & ~15) : 0;
    }

    // P2b: exclusive scan of s_cnt -> s_ofs (256 threads x chunks of 7)
    int v[7];
    int csum = 0;
    #pragma unroll
    for (int u = 0; u < 7; ++u) {
        int b = tid * 7 + u;
        v[u] = (b < NBUCK) ? s_cnt[b] : 0;
        csum += v[u];
    }
    s_sum[tid] = csum;
    __syncthreads();
    #pragma unroll
    for (int d = 1; d < 256; d <<= 1) {
        int t = (tid >= d) ? s_sum[tid - d] : 0;
        __syncthreads();
        s_sum[tid] += t;
        __syncthreads();
    }
    {
        int run = s_sum[tid] - csum;
        #pragma unroll
        for (int u = 0; u < 7; ++u) {
            int b = tid * 7 + u;
            if (b < NBUCK) { s_ofs[b] = run; run += v[u]; }
        }
    }
    __syncthreads();

    // P3: scatter packed words into LDS staging (s_ofs doubles as cursor;
    // after this phase s_ofs[b] = original_ofs + cnt)
    for (int i = tid; i < cntE; i += 256) {
        int s = ei[e0 + i];
        int d = ei[NE + e0 + i];
        int b = d >> 6;
        int pos = atomicAdd(&s_ofs[b], 1);
        s_stage[pos] = ((unsigned int)(d & 63) << 17) | (unsigned int)s;
    }
    __syncthreads();

    // P4: coalesced copy-out, sentinel-padded to aligned reservation
    const int wid = tid >> 6, lane = tid & 63;
    for (int b = wid; b < NBUCK; b += 4) {
        int cnt = s_cnt[b];
        if (!cnt) continue;
        int res = (cnt + 15) & ~15;
        int rdo = s_ofs[b] - cnt;                       // read base in stage
        int gb  = s_base[b];
        int lim = min(res, b * NPAD + NPAD - gb);       // overflow clamp (never hits)
        for (int j = lane; j < lim; j += 64)
            gbin[(size_t)gb + j] = (j < cnt) ? s_stage[rdo + j] : SENT;
    }
}

// ===========================================================================
// Fused gather-aggregate + GIN MLP.  One block per 64-node bucket (1563
// blocks -> ~6 blocks/CU, ~24 waves/CU).  One LANE per edge: 4 independent
// dwordx4 loads cover the full 64B feature row (4 random lines in flight
// per lane), plus one-slot run-word lookahead -> deep MLP for the latency-
// bound random gather.  LDS accumulate: 16 ds_add, addr=ld*17+j, 17*ld mod
// 32 is 2-to-1 -> <=2-way bank conflicts (free).  MLP epilogue in-block.
// ===========================================================================
__global__ __launch_bounds__(256) void k_gagg1(
    const float* __restrict__ feat, const unsigned int* __restrict__ gbin,
    const int* __restrict__ gcur,
    const float* __restrict__ b1, const float* __restrict__ w2,
    const float* __restrict__ b2, const float* __restrict__ w3,
    float* __restrict__ outfeat)
{
    __shared__ float s_acc[CNODES * 17];
    __shared__ float s_w2[HID * HID], s_w3[HID * HID], s_b1[HID], s_b2[HID];
    const int tid = threadIdx.x;
    const int b   = blockIdx.x;

    s_w2[tid] = w2[tid];
    s_w3[tid] = w3[tid];
    if (tid < HID) { s_b1[tid] = b1[tid]; s_b2[tid] = b2[tid]; }
    for (int i = tid; i < CNODES * 17; i += 256) s_acc[i] = 0.f;
    __syncthreads();

    const int nslots = min(gcur[b] - b * NPAD, NPAD);
    const unsigned int* run = gbin + (size_t)b * NPAD;
    const float4* pv = (const float4*)feat;

    int i = tid;
    unsigned int w = (i < nslots) ? run[i] : SENT;
    while (i < nslots) {
        int inx = i + 256;
        unsigned int wn = (inx < nslots) ? run[inx] : SENT;   // lookahead
        if (w != SENT) {
            int src = (int)(w & 0x1FFFFu);
            int ld  = (int)(w >> 17);
            float4 v0 = pv[(size_t)src * 4 + 0];
            float4 v1 = pv[(size_t)src * 4 + 1];
            float4 v2 = pv[(size_t)src * 4 + 2];
            float4 v3 = pv[(size_t)src * 4 + 3];
            float* a = s_acc + ld * 17;
            atomicAdd(a + 0,  v0.x); atomicAdd(a + 1,  v0.y);
            atomicAdd(a + 2,  v0.z); atomicAdd(a + 3,  v0.w);
            atomicAdd(a + 4,  v1.x); atomicAdd(a + 5,  v1.y);
            atomicAdd(a + 6,  v1.z); atomicAdd(a + 7,  v1.w);
            atomicAdd(a + 8,  v2.x); atomicAdd(a + 9,  v2.y);
            atomicAdd(a + 10, v2.z); atomicAdd(a + 11, v2.w);
            atomicAdd(a + 12, v3.x); atomicAdd(a + 13, v3.y);
            atomicAdd(a + 14, v3.z); atomicAdd(a + 15, v3.w);
        }
        w = wn;
        i = inx;
    }
    __syncthreads();

    const int node = b * CNODES + tid;
    if (tid < CNODES && node < NN) {
        const float4* fr = (const float4*)(feat + (size_t)node * HID);
        float t[HID];
        #pragma unroll
        for (int i2 = 0; i2 < 4; ++i2) {
            float4 f = fr[i2];
            t[i2*4+0] = fmaxf(f.x + s_acc[tid*17 + i2*4+0] + s_b1[i2*4+0], 0.f);
            t[i2*4+1] = fmaxf(f.y + s_acc[tid*17 + i2*4+1] + s_b1[i2*4+1], 0.f);
            t[i2*4+2] = fmaxf(f.z + s_acc[tid*17 + i2*4+2] + s_b1[i2*4+2], 0.f);
            t[i2*4+3] = fmaxf(f.w + s_acc[tid*17 + i2*4+3] + s_b1[i2*4+3], 0.f);
        }
        float h[HID];
        #pragma unroll
        for (int i2 = 0; i2 < HID; ++i2) {
            float acc = s_b2[i2];
            #pragma unroll
            for (int j = 0; j < HID; ++j) acc += t[j] * s_w2[i2 * HID + j];
            h[i2] = fmaxf(acc, 0.f);
        }
        float o[HID];
        #pragma unroll
        for (int i2 = 0; i2 < HID; ++i2) {
            float acc = 0.f;
            #pragma unroll
            for (int j = 0; j < HID; ++j) acc += h[j] * s_w3[i2 * HID + j];
            o[i2] = acc;
        }
        float4* po = (float4*)(outfeat + (size_t)node * HID);
        #pragma unroll
        for (int i2 = 0; i2 < 4; ++i2)
            po[i2] = make_float4(o[i2*4+0], o[i2*4+1], o[i2*4+2], o[i2*4+3]);
    }
}

__global__ __launch_bounds__(256) void k_gagg2(
    const float* __restrict__ feat, const unsigned int* __restrict__ gbin,
    const int* __restrict__ gcur,
    const float* __restrict__ b1, const float* __restrict__ w2,
    const float* __restrict__ b2, const float* __restrict__ row,
    const float* __restrict__ rob,
    float* __restrict__ out)
{
    __shared__ float s_acc[CNODES * 17];
    __shared__ float s_w2[HID * HID], s_b1[HID], s_b2[HID], s_ro[HID];
    const int tid = threadIdx.x;
    const int b   = blockIdx.x;

    s_w2[tid] = w2[tid];
    if (tid < HID) { s_b1[tid] = b1[tid]; s_b2[tid] = b2[tid]; s_ro[tid] = row[tid]; }
    for (int i = tid; i < CNODES * 17; i += 256) s_acc[i] = 0.f;
    __syncthreads();

    const int nslots = min(gcur[b] - b * NPAD, NPAD);
    const unsigned int* run = gbin + (size_t)b * NPAD;
    const float4* pv = (const float4*)feat;

    int i = tid;
    unsigned int w = (i < nslots) ? run[i] : SENT;
    while (i < nslots) {
        int inx = i + 256;
        unsigned int wn = (inx < nslots) ? run[inx] : SENT;
        if (w != SENT) {
            int src = (int)(w & 0x1FFFFu);
            int ld  = (int)(w >> 17);
            float4 v0 = pv[(size_t)src * 4 + 0];
            float4 v1 = pv[(size_t)src * 4 + 1];
            float4 v2 = pv[(size_t)src * 4 + 2];
            float4 v3 = pv[(size_t)src * 4 + 3];
            float* a = s_acc + ld * 17;
            atomicAdd(a + 0,  v0.x); atomicAdd(a + 1,  v0.y);
            atomicAdd(a + 2,  v0.z); atomicAdd(a + 3,  v0.w);
            atomicAdd(a + 4,  v1.x); atomicAdd(a + 5,  v1.y);
            atomicAdd(a + 6,  v1.z); atomicAdd(a + 7,  v1.w);
            atomicAdd(a + 8,  v2.x); atomicAdd(a + 9,  v2.y);
            atomicAdd(a + 10, v2.z); atomicAdd(a + 11, v2.w);
            atomicAdd(a + 12, v3.x); atomicAdd(a + 13, v3.y);
            atomicAdd(a + 14, v3.z); atomicAdd(a + 15, v3.w);
        }
        w = wn;
        i = inx;
    }
    __syncthreads();

    const int node = b * CNODES + tid;
    if (tid < CNODES && node < NN) {
        const float4* fr = (const float4*)(feat + (size_t)node * HID);
        float t[HID];
        #pragma unroll
        for (int i2 = 0; i2 < 4; ++i2) {
            float4 f = fr[i2];
            t[i2*4+0] = fmaxf(f.x + s_acc[tid*17 + i2*4+0] + s_b1[i2*4+0], 0.f);
            t[i2*4+1] = fmaxf(f.y + s_acc[tid*17 + i2*4+1] + s_b1[i2*4+1], 0.f);
            t[i2*4+2] = fmaxf(f.z + s_acc[tid*17 + i2*4+2] + s_b1[i2*4+2], 0.f);
            t[i2*4+3] = fmaxf(f.w + s_acc[tid*17 + i2*4+3] + s_b1[i2*4+3], 0.f);
        }
        float res = rob[0];
        #pragma unroll
        for (int i2 = 0; i2 < HID; ++i2) {
            float acc = s_b2[i2];
            #pragma unroll
            for (int j = 0; j < HID; ++j) acc += t[j] * s_w2[i2 * HID + j];
            res += acc * s_ro[i2];
        }
        out[node] = res;
    }
}

// ===========================================================================
// FALLBACK PATH kernels (workspace too small): per-node embed + atomic scatter
// ===========================================================================
__global__ __launch_bounds__(256) void k_embed(
    const float* __restrict__ x,
    const float* __restrict__ conv_w, const float* __restrict__ conv_b,
    const float* __restrict__ fc_w,   const float* __restrict__ fc_b,
    const float* __restrict__ g1w1,
    float* __restrict__ p1)
{
    __shared__ float s_x[4][TL];
    __shared__ float s_h[4][FLAT + 3];
    __shared__ float s_e[4][EMB];

    const int w    = threadIdx.x >> 6;
    const int lane = threadIdx.x & 63;
    const int node = blockIdx.x * 4 + w;

    const float2* xr = (const float2*)(x + (size_t)node * TL);
    float2 v = xr[lane];
    s_x[w][lane * 2 + 0] = v.x;
    s_x[w][lane * 2 + 1] = v.y;
    __syncthreads();

    for (int o = lane; o < FLAT; o += 64) {
        int c = o / CL;
        int t = o - c * CL;
        float acc = conv_b[c];
        #pragma unroll
        for (int k = 0; k < KW; ++k)
            acc += s_x[w][t * ST + k] * conv_w[c * KW + k];
        s_h[w][o] = fmaxf(acc, 0.f);
    }
    __syncthreads();

    if (lane < EMB) {
        float acc = fc_b[lane];
        const float* wr = fc_w + lane * FLAT;
        for (int j = 0; j < FLAT; ++j)
            acc += s_h[w][j] * wr[j];
        s_e[w][lane] = acc;
    }
    __syncthreads();

    if (lane < HID) {
        float acc = 0.f;
        const float* wr = g1w1 + lane * EMB;
        #pragma unroll
        for (int j = 0; j < EMB; ++j)
            acc += s_e[w][j] * wr[j];
        p1[(size_t)node * HID + lane] = acc;
    }
}

__global__ __launch_bounds__(256) void k_scatter(
    const float* __restrict__ p, const int* __restrict__ ei,
    float* __restrict__ agg)
{
    long long t = (long long)blockIdx.x * 256 + threadIdx.x;
    int e = (int)(t >> 4);
    int k = (int)(t & 15);
    if (e >= NE) return;
    int src = ei[e];
    int dst = ei[NE + e];
    float v = p[(size_t)src * HID + k];
    atomicAdd(agg + (size_t)dst * HID + k, v);
}

__global__ __launch_bounds__(256) void k_mlp1(
    const float* __restrict__ p1, const float* __restrict__ agg,
    const float* __restrict__ b1, const float* __restrict__ w2,
    const float* __restrict__ b2, const float* __restrict__ w3,
    float* __restrict__ p2)
{
    __shared__ float s_w2[HID * HID], s_w3[HID * HID], s_b1[HID], s_b2[HID];
    int tid = threadIdx.x;
    s_w2[tid] = w2[tid];
    s_w3[tid] = w3[tid];
    if (tid < HID) { s_b1[tid] = b1[tid]; s_b2[tid] = b2[tid]; }
    __syncthreads();

    int n = blockIdx.x * 256 + tid;
    if (n >= NN) return;

    float t[HID], h[HID];
    const float4* pa = (const float4*)(p1  + (size_t)n * HID);
    const float4* pb = (const float4*)(agg + (size_t)n * HID);
    #pragma unroll
    for (int i = 0; i < 4; ++i) {
        float4 a = pa[i], b = pb[i];
        t[i*4+0] = fmaxf(a.x + b.x + s_b1[i*4+0], 0.f);
        t[i*4+1] = fmaxf(a.y + b.y + s_b1[i*4+1], 0.f);
        t[i*4+2] = fmaxf(a.z + b.z + s_b1[i*4+2], 0.f);
        t[i*4+3] = fmaxf(a.w + b.w + s_b1[i*4+3], 0.f);
    }
    #pragma unroll
    for (int i = 0; i < HID; ++i) {
        float acc = s_b2[i];
        #pragma unroll
        for (int j = 0; j < HID; ++j) acc += t[j] * s_w2[i * HID + j];
        h[i] = fmaxf(acc, 0.f);
    }
    float o[HID];
    #pragma unroll
    for (int i = 0; i < HID; ++i) {
        float acc = 0.f;
        #pragma unroll
        for (int j = 0; j < HID; ++j) acc += h[j] * s_w3[i * HID + j];
        o[i] = acc;
    }
    float4* po = (float4*)(p2 + (size_t)n * HID);
    #pragma unroll
    for (int i = 0; i < 4; ++i)
        po[i] = make_float4(o[i*4+0], o[i*4+1], o[i*4+2], o[i*4+3]);
}

__global__ __launch_bounds__(256) void k_final(
    const float* __restrict__ p2, const float* __restrict__ agg2,
    const float* __restrict__ b1, const float* __restrict__ w2,
    const float* __restrict__ b2, const float* __restrict__ row,
    const float* __restrict__ rob,
    float* __restrict__ out)
{
    __shared__ float s_w2[HID * HID], s_b1[HID], s_b2[HID], s_ro[HID];
    int tid = threadIdx.x;
    s_w2[tid] = w2[tid];
    if (tid < HID) { s_b1[tid] = b1[tid]; s_b2[tid] = b2[tid]; s_ro[tid] = row[tid]; }
    __syncthreads();

    int n = blockIdx.x * 256 + tid;
    if (n >= NN) return;

    float t[HID];
    const float4* pa = (const float4*)(p2   + (size_t)n * HID);
    const float4* pb = (const float4*)(agg2 + (size_t)n * HID);
    #pragma unroll
    for (int i = 0; i < 4; ++i) {
        float4 a = pa[i], b = pb[i];
        t[i*4+0] = fmaxf(a.x + b.x + s_b1[i*4+0], 0.f);
        t[i*4+1] = fmaxf(a.y + b.y + s_b1[i*4+1], 0.f);
        t[i*4+2] = fmaxf(a.z + b.z + s_b1[i*4+2], 0.f);
        t[i*4+3] = fmaxf(a.w + b.w + s_b1[i*4+3], 0.f);
    }
    float res = rob[0];
    #pragma unroll
    for (int i = 0; i < HID; ++i) {
        float acc = s_b2[i];
        #pragma unroll
        for (int j = 0; j < HID; ++j) acc += t[j] * s_w2[i * HID + j];
        res += acc * s_ro[i];
    }
    out[n] = res;
}

// ===========================================================================
extern "C" void kernel_launch(void* const* d_in, const int* in_sizes, int n_in,
                              void* d_out, int out_size, void* d_ws, size_t ws_size,
                              hipStream_t stream)
{
    const float* x      = (const float*)d_in[0];
    const int*   ei     = (const int*)  d_in[1];
    const float* conv_w = (const float*)d_in[2];
    const float* conv_b = (const float*)d_in[3];
    const float* fc_w   = (const float*)d_in[4];
    const float* fc_b   = (const float*)d_in[5];
    const float* g1w1   = (const float*)d_in[6];
    const float* g1b1   = (const float*)d_in[7];
    const float* g1w2   = (const float*)d_in[8];
    const float* g1b2   = (const float*)d_in[9];
    const float* g2w1   = (const float*)d_in[10];
    const float* g2b1   = (const float*)d_in[11];
    const float* g2w2   = (const float*)d_in[12];
    const float* g2b2   = (const float*)d_in[13];
    const float* ro_w   = (const float*)d_in[14];
    const float* ro_b   = (const float*)d_in[15];
    float* out = (float*)d_out;

    // workspace layout:
    //   A    [NN*HID] f32       p1 (projected features)
    //   B    [NN*HID] f32       p2 (layer-2 projected features)
    //   wcT  [FLAT*HID] f32     combined fc+g1w1 weight
    //   bc   [16] f32           combined bias
    //   gcur [NBUCK] i32        bucket cursors
    //   bin  [NBUCK*NPAD] u32   packed (local_dst<<17)|src, bucketed by dst>>6
    float* A    = (float*)d_ws;
    float* B    = A + (size_t)NN * HID;
    float* wcT  = B + (size_t)NN * HID;
    float* bc   = wcT + (size_t)FLAT * HID;
    int*   gcur = (int*)(bc + 16);
    unsigned int* bin = (unsigned int*)(gcur + NBUCK);
    const size_t need = (size_t)((char*)(bin + (size_t)NBUCK * NPAD) - (char*)d_ws);

    if (ws_size >= need) {
        k_prep<<<1, 256, 0, stream>>>(g1w1, fc_w, fc_b, wcT, bc, gcur);
        k_convfc<<<NN / 32, 256, 0, stream>>>(x, conv_w, conv_b, wcT, bc, A);
        k_bin<<<NBIN, 256, 0, stream>>>(ei, gcur, bin);
        // GIN layer 1: fused gather-aggregate + MLP + layer-2 projection
        k_gagg1<<<NBUCK, 256, 0, stream>>>(A, bin, gcur, g1b1, g1w2, g1b2,
                                           g2w1, B);
        // GIN layer 2: fused gather-aggregate + MLP + readout
        k_gagg2<<<NBUCK, 256, 0, stream>>>(B, bin, gcur, g2b1, g2w2, g2b2,
                                           ro_w, ro_b, out);
    } else {
        // --- fallback: fused per-node embed + atomic scatter ---
        k_embed<<<NN / 4, 256, 0, stream>>>(x, conv_w, conv_b, fc_w, fc_b,
                                            g1w1, A);
        hipMemsetAsync(B, 0, (size_t)NN * HID * sizeof(float), stream);
        k_scatter<<<(int)(((long long)NE * HID) / 256), 256, 0, stream>>>(A, ei, B);
        k_mlp1<<<(NN + 255) / 256, 256, 0, stream>>>(A, B, g1b1, g1w2, g1b2,
                                                     g2w1, A);
        hipMemsetAsync(B, 0, (size_t)NN * HID * sizeof(float), stream);
        k_scatter<<<(int)(((long long)NE * HID) / 256), 256, 0, stream>>>(A, ei, B);
        k_final<<<(NN + 255) / 256, 256, 0, stream>>>(A, B, g2b1, g2w2, g2b2,
                                                      ro_w, ro_b, out);
    }
}

// Round 5
// 469.176 us; speedup vs baseline: 2.0105x; 1.9770x over previous
//
#include <hip/hip_runtime.h>

#define NN   100000
#define TL   128
#define OC   5
#define KW   7
#define ST   3
#define CL   41          // (128-7)/3+1
#define FLAT 205         // 5*41
#define EMB  32
#define HID  16
#define NE   3200000

#define CNODES 64                // nodes per bucket (dst>>6)
#define NBUCK  1563              // ceil(NN/64)
#define NPAD   4096              // bucket slot capacity (mean fill ~3400, +12 sigma)
#define NS     2560              // sorted-src capacity per bucket (mean 2048, +11 sigma)
#define TILE   16384             // edges per k_bin block
#define NBIN   196               // ceil(NE/TILE)
#define SENT   0xFFFFFFFFu       // sentinel slot (real words are < 2^23)

__device__ __forceinline__ void f4add(float4& a, const float4 v) {
    a.x += v.x; a.y += v.y; a.z += v.z; a.w += v.w;
}

// ===========================================================================
// Precompute combined weight Wc = g1w1 @ fc_w  ([16 x 205], j-major wcT) and
// bc = g1w1 @ fc_b.  Also init per-bucket bin cursors gcur[b] = b*NPAD.
// ===========================================================================
__global__ __launch_bounds__(256) void k_prep(
    const float* __restrict__ g1w1, const float* __restrict__ fc_w,
    const float* __restrict__ fc_b,
    float* __restrict__ wcT, float* __restrict__ bc,
    int* __restrict__ gcur)
{
    int tid = threadIdx.x;
    for (int idx = tid; idx < FLAT * HID; idx += 256) {
        int l = idx & 15;
        int j = idx >> 4;
        float s = 0.f;
        #pragma unroll
        for (int m = 0; m < EMB; ++m)
            s = fmaf(g1w1[l * EMB + m], fc_w[m * FLAT + j], s);
        wcT[j * HID + l] = s;
    }
    if (tid < HID) {
        float s = 0.f;
        #pragma unroll
        for (int m = 0; m < EMB; ++m)
            s = fmaf(g1w1[tid * EMB + m], fc_b[m], s);
        bc[tid] = s;
    }
    for (int b = tid; b < NBUCK; b += 256)
        gcur[b] = b * NPAD;
}

// ===========================================================================
// Fused Conv1d+ReLU+FC(+g1w1): 32-node tile per block (unchanged, verified).
// ===========================================================================
__global__ __launch_bounds__(256) void k_convfc(
    const float* __restrict__ x,
    const float* __restrict__ conv_w, const float* __restrict__ conv_b,
    const float* __restrict__ wcT,   const float* __restrict__ bc,
    float* __restrict__ p1)
{
    __shared__ float s_x[32 * 129];
    __shared__ float s_h[FLAT * 32];
    const int tid = threadIdx.x;
    const long long n0 = (long long)blockIdx.x * 32;   // NN = 32*3125 exact

    const float4* xv = (const float4*)(x + n0 * TL);
    #pragma unroll
    for (int c = 0; c < 4; ++c) {
        int f4  = c * 256 + tid;
        int row = f4 >> 5;
        int c4  = f4 & 31;
        float4 v = xv[f4];
        float* d = s_x + row * 129 + c4 * 4;
        d[0] = v.x; d[1] = v.y; d[2] = v.z; d[3] = v.w;
    }
    __syncthreads();

    for (int idx = tid; idx < FLAT * 32; idx += 256) {
        int n = idx & 31;
        int o = idx >> 5;
        int c = o / CL;
        int t = o - c * CL;
        float acc = conv_b[c];
        const float* wr = conv_w + c * KW;
        const float* xr = s_x + n * 129 + t * ST;
        #pragma unroll
        for (int k = 0; k < KW; ++k)
            acc = fmaf(xr[k], wr[k], acc);
        s_h[o * 32 + n] = fmaxf(acc, 0.f);
    }
    __syncthreads();

    const int l  = tid & 15;
    const int n2 = tid >> 4;
    float a0 = bc[l];
    float a1 = a0;
    #pragma unroll 5
    for (int j = 0; j < FLAT; ++j) {
        float w = wcT[j * HID + l];
        a0 = fmaf(s_h[j * 32 + n2],      w, a0);
        a1 = fmaf(s_h[j * 32 + n2 + 16], w, a1);
    }
    p1[(n0 + n2)      * HID + l] = a0;
    p1[(n0 + n2 + 16) * HID + l] = a1;
}

// ===========================================================================
// LDS-staged bucket binning, line-exclusive output chunks (unchanged).
// ===========================================================================
__global__ __launch_bounds__(256) void k_bin(
    const int* __restrict__ ei, int* __restrict__ gcur,
    unsigned int* __restrict__ gbin)
{
    __shared__ unsigned int s_stage[TILE];
    __shared__ int s_cnt[NBUCK], s_ofs[NBUCK], s_base[NBUCK];
    __shared__ int s_sum[256];

    const int tid = threadIdx.x;
    const int e0  = blockIdx.x * TILE;
    const int cntE = min(TILE, NE - e0);

    for (int b = tid; b < NBUCK; b += 256) s_cnt[b] = 0;
    __syncthreads();

    // P1: histogram
    for (int i = tid; i < cntE; i += 256)
        atomicAdd(&s_cnt[ei[NE + e0 + i] >> 6], 1);
    __syncthreads();

    // P2a: aligned global reservation (one atomic per nonempty bucket)
    for (int b = tid; b < NBUCK; b += 256) {
        int c = s_cnt[b];
        s_base[b] = c ? atomicAdd(&gcur[b], (c + 15) & ~15) : 0;
    }

    // P2b: exclusive scan of s_cnt -> s_ofs
    int v[7];
    int csum = 0;
    #pragma unroll
    for (int u = 0; u < 7; ++u) {
        int b = tid * 7 + u;
        v[u] = (b < NBUCK) ? s_cnt[b] : 0;
        csum += v[u];
    }
    s_sum[tid] = csum;
    __syncthreads();
    #pragma unroll
    for (int d = 1; d < 256; d <<= 1) {
        int t = (tid >= d) ? s_sum[tid - d] : 0;
        __syncthreads();
        s_sum[tid] += t;
        __syncthreads();
    }
    {
        int run = s_sum[tid] - csum;
        #pragma unroll
        for (int u = 0; u < 7; ++u) {
            int b = tid * 7 + u;
            if (b < NBUCK) { s_ofs[b] = run; run += v[u]; }
        }
    }
    __syncthreads();

    // P3: scatter packed words into LDS staging
    for (int i = tid; i < cntE; i += 256) {
        int s = ei[e0 + i];
        int d = ei[NE + e0 + i];
        int b = d >> 6;
        int pos = atomicAdd(&s_ofs[b], 1);
        s_stage[pos] = ((unsigned int)(d & 63) << 17) | (unsigned int)s;
    }
    __syncthreads();

    // P4: coalesced copy-out, sentinel-padded to aligned reservation
    const int wid = tid >> 6, lane = tid & 63;
    for (int b = wid; b < NBUCK; b += 4) {
        int cnt = s_cnt[b];
        if (!cnt) continue;
        int res = (cnt + 15) & ~15;
        int rdo = s_ofs[b] - cnt;
        int gb  = s_base[b];
        int lim = min(res, b * NPAD + NPAD - gb);
        for (int j = lane; j < lim; j += 64)
            gbin[(size_t)gb + j] = (j < cnt) ? s_stage[rdo + j] : SENT;
    }
}

// ===========================================================================
// Per-bucket counting sort by local node (once; reused by both layers).
// One block per 64-node bucket.  Stage slots in LDS; histogram + scan over
// 64 counters (INT LDS atomics, 2 per edge total); scatter srcs to a
// block-exclusive global region (L2-hot, full-line writeback); write 65
// per-node offsets.  Output: gsorted (dst-sorted srcs), goff.
// ===========================================================================
__global__ __launch_bounds__(256) void k_sort(
    const unsigned int* __restrict__ gbin, const int* __restrict__ gcur,
    int* __restrict__ goff, int* __restrict__ gsorted)
{
    __shared__ unsigned int s_stage[NPAD];      // 16 KB
    __shared__ int s_cnt[CNODES], s_ofs[CNODES], s_loc[CNODES];
    const int tid = threadIdx.x;
    const int b   = blockIdx.x;
    const int nslots = min(gcur[b] - b * NPAD, NPAD);
    const unsigned int* run = gbin + (size_t)b * NPAD;

    if (tid < CNODES) s_cnt[tid] = 0;
    __syncthreads();

    // load + histogram
    for (int i = tid; i < nslots; i += 256) {
        unsigned int w = run[i];
        s_stage[i] = w;
        if (w != SENT) atomicAdd(&s_cnt[w >> 17], 1);
    }
    __syncthreads();

    // inclusive Hillis-Steele scan over 64 counters
    if (tid < CNODES) s_ofs[tid] = s_cnt[tid];
    __syncthreads();
    #pragma unroll
    for (int d = 1; d < CNODES; d <<= 1) {
        int t = (tid < CNODES && tid >= d) ? s_ofs[tid - d] : 0;
        __syncthreads();
        if (tid < CNODES) s_ofs[tid] += t;
        __syncthreads();
    }
    if (tid < CNODES) {
        int inc = s_ofs[tid];
        s_loc[tid] = inc - s_cnt[tid];                   // exclusive
        goff[(size_t)b * 65 + tid + 1] = min(inc, NS);   // clamp (never hits)
    }
    if (tid == 0) goff[(size_t)b * 65] = 0;
    __syncthreads();

    // scatter srcs into block-exclusive sorted region
    int* dst = gsorted + (size_t)b * NS;
    for (int i = tid; i < nslots; i += 256) {
        unsigned int w = s_stage[i];
        if (w != SENT) {
            int pos = atomicAdd(&s_loc[w >> 17], 1);
            if (pos < NS) dst[pos] = (int)(w & 0x1FFFFu);
        }
    }
}

// ===========================================================================
// Fused gather-aggregate + GIN MLP, ATOMIC-FREE.  One block per 64-node
// bucket; thread = (node = tid>>2, quad = tid&3).  Walk the node's sorted
// src run with 4-wide unrolled independent float4 loads (4 lanes of a node
// share each 64B line -> 1 request/edge), accumulate in REGISTERS, one
// plain LDS store, then per-node MLP epilogue in-block.
// ===========================================================================
__global__ __launch_bounds__(256) void k_gagg1(
    const float* __restrict__ feat, const int* __restrict__ goff,
    const int* __restrict__ gsorted,
    const float* __restrict__ b1, const float* __restrict__ w2,
    const float* __restrict__ b2, const float* __restrict__ w3,
    float* __restrict__ outfeat)
{
    __shared__ float s_acc[CNODES * 16];
    __shared__ float s_w2[HID * HID], s_w3[HID * HID], s_b1[HID], s_b2[HID];
    __shared__ int s_off[CNODES + 1];
    const int tid = threadIdx.x;
    const int b   = blockIdx.x;

    s_w2[tid] = w2[tid];
    s_w3[tid] = w3[tid];
    if (tid < HID) { s_b1[tid] = b1[tid]; s_b2[tid] = b2[tid]; }
    if (tid < CNODES + 1) s_off[tid] = goff[(size_t)b * 65 + tid];
    __syncthreads();

    const int node = tid >> 2, q = tid & 3;
    const int* srcs = gsorted + (size_t)b * NS;
    const float4* pv = (const float4*)feat;
    float4 acc0 = make_float4(0.f, 0.f, 0.f, 0.f);
    float4 acc1 = make_float4(0.f, 0.f, 0.f, 0.f);
    int j = s_off[node];
    const int e = s_off[node + 1];
    for (; j + 3 < e; j += 4) {
        int s0 = srcs[j], s1 = srcs[j + 1], s2 = srcs[j + 2], s3 = srcs[j + 3];
        float4 v0 = pv[(size_t)s0 * 4 + q];
        float4 v1 = pv[(size_t)s1 * 4 + q];
        float4 v2 = pv[(size_t)s2 * 4 + q];
        float4 v3 = pv[(size_t)s3 * 4 + q];
        f4add(acc0, v0); f4add(acc1, v1); f4add(acc0, v2); f4add(acc1, v3);
    }
    for (; j < e; ++j)
        f4add(acc0, pv[(size_t)srcs[j] * 4 + q]);
    f4add(acc0, acc1);
    ((float4*)s_acc)[node * 4 + q] = acc0;
    __syncthreads();

    const int gn = b * CNODES + tid;
    if (tid < CNODES && gn < NN) {
        const float4* fr = (const float4*)(feat + (size_t)gn * HID);
        const float4* sa = (const float4*)(s_acc + tid * 16);
        float t[HID];
        #pragma unroll
        for (int i2 = 0; i2 < 4; ++i2) {
            float4 f = fr[i2], a = sa[i2];
            t[i2*4+0] = fmaxf(f.x + a.x + s_b1[i2*4+0], 0.f);
            t[i2*4+1] = fmaxf(f.y + a.y + s_b1[i2*4+1], 0.f);
            t[i2*4+2] = fmaxf(f.z + a.z + s_b1[i2*4+2], 0.f);
            t[i2*4+3] = fmaxf(f.w + a.w + s_b1[i2*4+3], 0.f);
        }
        float h[HID];
        #pragma unroll
        for (int i2 = 0; i2 < HID; ++i2) {
            float acc = s_b2[i2];
            #pragma unroll
            for (int jj = 0; jj < HID; ++jj) acc += t[jj] * s_w2[i2 * HID + jj];
            h[i2] = fmaxf(acc, 0.f);
        }
        float o[HID];
        #pragma unroll
        for (int i2 = 0; i2 < HID; ++i2) {
            float acc = 0.f;
            #pragma unroll
            for (int jj = 0; jj < HID; ++jj) acc += h[jj] * s_w3[i2 * HID + jj];
            o[i2] = acc;
        }
        float4* po = (float4*)(outfeat + (size_t)gn * HID);
        #pragma unroll
        for (int i2 = 0; i2 < 4; ++i2)
            po[i2] = make_float4(o[i2*4+0], o[i2*4+1], o[i2*4+2], o[i2*4+3]);
    }
}

__global__ __launch_bounds__(256) void k_gagg2(
    const float* __restrict__ feat, const int* __restrict__ goff,
    const int* __restrict__ gsorted,
    const float* __restrict__ b1, const float* __restrict__ w2,
    const float* __restrict__ b2, const float* __restrict__ row,
    const float* __restrict__ rob,
    float* __restrict__ out)
{
    __shared__ float s_acc[CNODES * 16];
    __shared__ float s_w2[HID * HID], s_b1[HID], s_b2[HID], s_ro[HID];
    __shared__ int s_off[CNODES + 1];
    const int tid = threadIdx.x;
    const int b   = blockIdx.x;

    s_w2[tid] = w2[tid];
    if (tid < HID) { s_b1[tid] = b1[tid]; s_b2[tid] = b2[tid]; s_ro[tid] = row[tid]; }
    if (tid < CNODES + 1) s_off[tid] = goff[(size_t)b * 65 + tid];
    __syncthreads();

    const int node = tid >> 2, q = tid & 3;
    const int* srcs = gsorted + (size_t)b * NS;
    const float4* pv = (const float4*)feat;
    float4 acc0 = make_float4(0.f, 0.f, 0.f, 0.f);
    float4 acc1 = make_float4(0.f, 0.f, 0.f, 0.f);
    int j = s_off[node];
    const int e = s_off[node + 1];
    for (; j + 3 < e; j += 4) {
        int s0 = srcs[j], s1 = srcs[j + 1], s2 = srcs[j + 2], s3 = srcs[j + 3];
        float4 v0 = pv[(size_t)s0 * 4 + q];
        float4 v1 = pv[(size_t)s1 * 4 + q];
        float4 v2 = pv[(size_t)s2 * 4 + q];
        float4 v3 = pv[(size_t)s3 * 4 + q];
        f4add(acc0, v0); f4add(acc1, v1); f4add(acc0, v2); f4add(acc1, v3);
    }
    for (; j < e; ++j)
        f4add(acc0, pv[(size_t)srcs[j] * 4 + q]);
    f4add(acc0, acc1);
    ((float4*)s_acc)[node * 4 + q] = acc0;
    __syncthreads();

    const int gn = b * CNODES + tid;
    if (tid < CNODES && gn < NN) {
        const float4* fr = (const float4*)(feat + (size_t)gn * HID);
        const float4* sa = (const float4*)(s_acc + tid * 16);
        float t[HID];
        #pragma unroll
        for (int i2 = 0; i2 < 4; ++i2) {
            float4 f = fr[i2], a = sa[i2];
            t[i2*4+0] = fmaxf(f.x + a.x + s_b1[i2*4+0], 0.f);
            t[i2*4+1] = fmaxf(f.y + a.y + s_b1[i2*4+1], 0.f);
            t[i2*4+2] = fmaxf(f.z + a.z + s_b1[i2*4+2], 0.f);
            t[i2*4+3] = fmaxf(f.w + a.w + s_b1[i2*4+3], 0.f);
        }
        float res = rob[0];
        #pragma unroll
        for (int i2 = 0; i2 < HID; ++i2) {
            float acc = s_b2[i2];
            #pragma unroll
            for (int jj = 0; jj < HID; ++jj) acc += t[jj] * s_w2[i2 * HID + jj];
            res += acc * s_ro[i2];
        }
        out[gn] = res;
    }
}

// ===========================================================================
// FALLBACK PATH kernels (workspace too small): per-node embed + atomic scatter
// ===========================================================================
__global__ __launch_bounds__(256) void k_embed(
    const float* __restrict__ x,
    const float* __restrict__ conv_w, const float* __restrict__ conv_b,
    const float* __restrict__ fc_w,   const float* __restrict__ fc_b,
    const float* __restrict__ g1w1,
    float* __restrict__ p1)
{
    __shared__ float s_x[4][TL];
    __shared__ float s_h[4][FLAT + 3];
    __shared__ float s_e[4][EMB];

    const int w    = threadIdx.x >> 6;
    const int lane = threadIdx.x & 63;
    const int node = blockIdx.x * 4 + w;

    const float2* xr = (const float2*)(x + (size_t)node * TL);
    float2 v = xr[lane];
    s_x[w][lane * 2 + 0] = v.x;
    s_x[w][lane * 2 + 1] = v.y;
    __syncthreads();

    for (int o = lane; o < FLAT; o += 64) {
        int c = o / CL;
        int t = o - c * CL;
        float acc = conv_b[c];
        #pragma unroll
        for (int k = 0; k < KW; ++k)
            acc += s_x[w][t * ST + k] * conv_w[c * KW + k];
        s_h[w][o] = fmaxf(acc, 0.f);
    }
    __syncthreads();

    if (lane < EMB) {
        float acc = fc_b[lane];
        const float* wr = fc_w + lane * FLAT;
        for (int j = 0; j < FLAT; ++j)
            acc += s_h[w][j] * wr[j];
        s_e[w][lane] = acc;
    }
    __syncthreads();

    if (lane < HID) {
        float acc = 0.f;
        const float* wr = g1w1 + lane * EMB;
        #pragma unroll
        for (int j = 0; j < EMB; ++j)
            acc += s_e[w][j] * wr[j];
        p1[(size_t)node * HID + lane] = acc;
    }
}

__global__ __launch_bounds__(256) void k_scatter(
    const float* __restrict__ p, const int* __restrict__ ei,
    float* __restrict__ agg)
{
    long long t = (long long)blockIdx.x * 256 + threadIdx.x;
    int e = (int)(t >> 4);
    int k = (int)(t & 15);
    if (e >= NE) return;
    int src = ei[e];
    int dst = ei[NE + e];
    float v = p[(size_t)src * HID + k];
    atomicAdd(agg + (size_t)dst * HID + k, v);
}

__global__ __launch_bounds__(256) void k_mlp1(
    const float* __restrict__ p1, const float* __restrict__ agg,
    const float* __restrict__ b1, const float* __restrict__ w2,
    const float* __restrict__ b2, const float* __restrict__ w3,
    float* __restrict__ p2)
{
    __shared__ float s_w2[HID * HID], s_w3[HID * HID], s_b1[HID], s_b2[HID];
    int tid = threadIdx.x;
    s_w2[tid] = w2[tid];
    s_w3[tid] = w3[tid];
    if (tid < HID) { s_b1[tid] = b1[tid]; s_b2[tid] = b2[tid]; }
    __syncthreads();

    int n = blockIdx.x * 256 + tid;
    if (n >= NN) return;

    float t[HID], h[HID];
    const float4* pa = (const float4*)(p1  + (size_t)n * HID);
    const float4* pb = (const float4*)(agg + (size_t)n * HID);
    #pragma unroll
    for (int i = 0; i < 4; ++i) {
        float4 a = pa[i], b = pb[i];
        t[i*4+0] = fmaxf(a.x + b.x + s_b1[i*4+0], 0.f);
        t[i*4+1] = fmaxf(a.y + b.y + s_b1[i*4+1], 0.f);
        t[i*4+2] = fmaxf(a.z + b.z + s_b1[i*4+2], 0.f);
        t[i*4+3] = fmaxf(a.w + b.w + s_b1[i*4+3], 0.f);
    }
    #pragma unroll
    for (int i = 0; i < HID; ++i) {
        float acc = s_b2[i];
        #pragma unroll
        for (int j = 0; j < HID; ++j) acc += t[j] * s_w2[i * HID + j];
        h[i] = fmaxf(acc, 0.f);
    }
    float o[HID];
    #pragma unroll
    for (int i = 0; i < HID; ++i) {
        float acc = 0.f;
        #pragma unroll
        for (int j = 0; j < HID; ++j) acc += h[j] * s_w3[i * HID + j];
        o[i] = acc;
    }
    float4* po = (float4*)(p2 + (size_t)n * HID);
    #pragma unroll
    for (int i = 0; i < 4; ++i)
        po[i] = make_float4(o[i*4+0], o[i*4+1], o[i*4+2], o[i*4+3]);
}

__global__ __launch_bounds__(256) void k_final(
    const float* __restrict__ p2, const float* __restrict__ agg2,
    const float* __restrict__ b1, const float* __restrict__ w2,
    const float* __restrict__ b2, const float* __restrict__ row,
    const float* __restrict__ rob,
    float* __restrict__ out)
{
    __shared__ float s_w2[HID * HID], s_b1[HID], s_b2[HID], s_ro[HID];
    int tid = threadIdx.x;
    s_w2[tid] = w2[tid];
    if (tid < HID) { s_b1[tid] = b1[tid]; s_b2[tid] = b2[tid]; s_ro[tid] = row[tid]; }
    __syncthreads();

    int n = blockIdx.x * 256 + tid;
    if (n >= NN) return;

    float t[HID];
    const float4* pa = (const float4*)(p2   + (size_t)n * HID);
    const float4* pb = (const float4*)(agg2 + (size_t)n * HID);
    #pragma unroll
    for (int i = 0; i < 4; ++i) {
        float4 a = pa[i], b = pb[i];
        t[i*4+0] = fmaxf(a.x + b.x + s_b1[i*4+0], 0.f);
        t[i*4+1] = fmaxf(a.y + b.y + s_b1[i*4+1], 0.f);
        t[i*4+2] = fmaxf(a.z + b.z + s_b1[i*4+2], 0.f);
        t[i*4+3] = fmaxf(a.w + b.w + s_b1[i*4+3], 0.f);
    }
    float res = rob[0];
    #pragma unroll
    for (int i = 0; i < HID; ++i) {
        float acc = s_b2[i];
        #pragma unroll
        for (int j = 0; j < HID; ++j) acc += t[j] * s_w2[i * HID + j];
        res += acc * s_ro[i];
    }
    out[n] = res;
}

// ===========================================================================
extern "C" void kernel_launch(void* const* d_in, const int* in_sizes, int n_in,
                              void* d_out, int out_size, void* d_ws, size_t ws_size,
                              hipStream_t stream)
{
    const float* x      = (const float*)d_in[0];
    const int*   ei     = (const int*)  d_in[1];
    const float* conv_w = (const float*)d_in[2];
    const float* conv_b = (const float*)d_in[3];
    const float* fc_w   = (const float*)d_in[4];
    const float* fc_b   = (const float*)d_in[5];
    const float* g1w1   = (const float*)d_in[6];
    const float* g1b1   = (const float*)d_in[7];
    const float* g1w2   = (const float*)d_in[8];
    const float* g1b2   = (const float*)d_in[9];
    const float* g2w1   = (const float*)d_in[10];
    const float* g2b1   = (const float*)d_in[11];
    const float* g2w2   = (const float*)d_in[12];
    const float* g2b2   = (const float*)d_in[13];
    const float* ro_w   = (const float*)d_in[14];
    const float* ro_b   = (const float*)d_in[15];
    float* out = (float*)d_out;

    // workspace layout:
    //   A       [NN*HID] f32        p1 (projected features)
    //   B       [NN*HID] f32        p2 (layer-2 projected features)
    //   wcT     [FLAT*HID] f32      combined fc+g1w1 weight
    //   bc      [16] f32            combined bias
    //   gcur    [NBUCK] i32         bin cursors
    //   gbin    [NBUCK*NPAD] u32    packed (local_dst<<17)|src per bucket
    //   goff    [NBUCK*65] i32      per-node offsets within bucket
    //   gsorted [NBUCK*NS] i32      dst-sorted src ids per bucket
    float* A    = (float*)d_ws;
    float* B    = A + (size_t)NN * HID;
    float* wcT  = B + (size_t)NN * HID;
    float* bc   = wcT + (size_t)FLAT * HID;
    int*   gcur = (int*)(bc + 16);
    unsigned int* gbin = (unsigned int*)(gcur + NBUCK);
    int*   goff    = (int*)(gbin + (size_t)NBUCK * NPAD);
    int*   gsorted = goff + (size_t)NBUCK * 65;
    const size_t need = (size_t)((char*)(gsorted + (size_t)NBUCK * NS) - (char*)d_ws);

    if (ws_size >= need) {
        k_prep<<<1, 256, 0, stream>>>(g1w1, fc_w, fc_b, wcT, bc, gcur);
        k_convfc<<<NN / 32, 256, 0, stream>>>(x, conv_w, conv_b, wcT, bc, A);
        k_bin<<<NBIN, 256, 0, stream>>>(ei, gcur, gbin);
        k_sort<<<NBUCK, 256, 0, stream>>>(gbin, gcur, goff, gsorted);
        // GIN layer 1: atomic-free gather + MLP + layer-2 projection
        k_gagg1<<<NBUCK, 256, 0, stream>>>(A, goff, gsorted, g1b1, g1w2, g1b2,
                                           g2w1, B);
        // GIN layer 2: atomic-free gather + MLP + readout
        k_gagg2<<<NBUCK, 256, 0, stream>>>(B, goff, gsorted, g2b1, g2w2, g2b2,
                                           ro_w, ro_b, out);
    } else {
        // --- fallback: fused per-node embed + atomic scatter ---
        k_embed<<<NN / 4, 256, 0, stream>>>(x, conv_w, conv_b, fc_w, fc_b,
                                            g1w1, A);
        hipMemsetAsync(B, 0, (size_t)NN * HID * sizeof(float), stream);
        k_scatter<<<(int)(((long long)NE * HID) / 256), 256, 0, stream>>>(A, ei, B);
        k_mlp1<<<(NN + 255) / 256, 256, 0, stream>>>(A, B, g1b1, g1w2, g1b2,
                                                     g2w1, A);
        hipMemsetAsync(B, 0, (size_t)NN * HID * sizeof(float), stream);
        k_scatter<<<(int)(((long long)NE * HID) / 256), 256, 0, stream>>>(A, ei, B);
        k_final<<<(NN + 255) / 256, 256, 0, stream>>>(A, B, g2b1, g2w2, g2b2,
                                                      ro_w, ro_b, out);
    }
}

// Round 6
// 367.298 us; speedup vs baseline: 2.5681x; 1.2774x over previous
//
#include <hip/hip_runtime.h>

#define NN   100000
#define TL   128
#define OC   5
#define KW   7
#define ST   3
#define CL   41          // (128-7)/3+1
#define FLAT 205         // 5*41
#define EMB  32
#define HID  16
#define NE   3200000

#define BBUCK  391               // bin buckets (256 nodes each, dst>>8)
#define NPB    14336             // slots per bin bucket (mean fill ~12980, +16 sigma)
#define TILE   4096              // edges per k_bin block
#define NBIN   782               // ceil(NE/TILE)
#define CNODES 64                // nodes per gagg/sort bucket
#define NGB    1563              // ceil(NN/64)
#define NS     2560              // sorted-src capacity per 64-node bucket (mean 2048)
#define SENT   0xFFFFFFFFu       // sentinel slot (real words are < 2^26)

__device__ __forceinline__ void f4add(float4& a, const float4 v) {
    a.x += v.x; a.y += v.y; a.z += v.z; a.w += v.w;
}

// ===========================================================================
// Precompute combined weight Wc = g1w1 @ fc_w  ([16 x 205], j-major wcT) and
// bc = g1w1 @ fc_b.  Also init per-bucket bin cursors gcur[b] = b*NPB.
// ===========================================================================
__global__ __launch_bounds__(256) void k_prep(
    const float* __restrict__ g1w1, const float* __restrict__ fc_w,
    const float* __restrict__ fc_b,
    float* __restrict__ wcT, float* __restrict__ bc,
    int* __restrict__ gcur)
{
    int tid = threadIdx.x;
    for (int idx = tid; idx < FLAT * HID; idx += 256) {
        int l = idx & 15;
        int j = idx >> 4;
        float s = 0.f;
        #pragma unroll
        for (int m = 0; m < EMB; ++m)
            s = fmaf(g1w1[l * EMB + m], fc_w[m * FLAT + j], s);
        wcT[j * HID + l] = s;
    }
    if (tid < HID) {
        float s = 0.f;
        #pragma unroll
        for (int m = 0; m < EMB; ++m)
            s = fmaf(g1w1[tid * EMB + m], fc_b[m], s);
        bc[tid] = s;
    }
    for (int b = tid; b < BBUCK; b += 256)
        gcur[b] = b * NPB;
}

// ===========================================================================
// Fused Conv1d+ReLU+FC(+g1w1): 32-node tile per block (unchanged, verified).
// ===========================================================================
__global__ __launch_bounds__(256) void k_convfc(
    const float* __restrict__ x,
    const float* __restrict__ conv_w, const float* __restrict__ conv_b,
    const float* __restrict__ wcT,   const float* __restrict__ bc,
    float* __restrict__ p1)
{
    __shared__ float s_x[32 * 129];
    __shared__ float s_h[FLAT * 32];
    const int tid = threadIdx.x;
    const long long n0 = (long long)blockIdx.x * 32;   // NN = 32*3125 exact

    const float4* xv = (const float4*)(x + n0 * TL);
    #pragma unroll
    for (int c = 0; c < 4; ++c) {
        int f4  = c * 256 + tid;
        int row = f4 >> 5;
        int c4  = f4 & 31;
        float4 v = xv[f4];
        float* d = s_x + row * 129 + c4 * 4;
        d[0] = v.x; d[1] = v.y; d[2] = v.z; d[3] = v.w;
    }
    __syncthreads();

    for (int idx = tid; idx < FLAT * 32; idx += 256) {
        int n = idx & 31;
        int o = idx >> 5;
        int c = o / CL;
        int t = o - c * CL;
        float acc = conv_b[c];
        const float* wr = conv_w + c * KW;
        const float* xr = s_x + n * 129 + t * ST;
        #pragma unroll
        for (int k = 0; k < KW; ++k)
            acc = fmaf(xr[k], wr[k], acc);
        s_h[o * 32 + n] = fmaxf(acc, 0.f);
    }
    __syncthreads();

    const int l  = tid & 15;
    const int n2 = tid >> 4;
    float a0 = bc[l];
    float a1 = a0;
    #pragma unroll 5
    for (int j = 0; j < FLAT; ++j) {
        float w = wcT[j * HID + l];
        a0 = fmaf(s_h[j * 32 + n2],      w, a0);
        a1 = fmaf(s_h[j * 32 + n2 + 16], w, a1);
    }
    p1[(n0 + n2)      * HID + l] = a0;
    p1[(n0 + n2 + 16) * HID + l] = a1;
}

// ===========================================================================
// LDS-staged bucket binning v2: 391 buckets of 256 nodes (dst>>8), 4096-edge
// tiles.  LDS ~22KB -> 7 blocks/CU resident, grid 782 -> ~3 running/CU
// (r5's version was 84KB/1 block/CU, grid 196 -> latency-starved at 8% occ).
// Line-exclusive 16-word-aligned reservations as before (no cross-XCD
// partial-line writeback); sentinel-padded runs.
// ===========================================================================
__global__ __launch_bounds__(256) void k_bin(
    const int* __restrict__ ei, int* __restrict__ gcur,
    unsigned int* __restrict__ gbin)
{
    __shared__ unsigned int s_stage[TILE];                 // 16 KB
    __shared__ int s_cnt[BBUCK], s_ofs[BBUCK], s_base[BBUCK];  // 4.7 KB
    __shared__ int s_sum[256];

    const int tid = threadIdx.x;
    const int e0  = blockIdx.x * TILE;
    const int cntE = min(TILE, NE - e0);

    for (int b = tid; b < BBUCK; b += 256) s_cnt[b] = 0;
    __syncthreads();

    // P1: histogram over 391 buckets
    for (int i = tid; i < cntE; i += 256)
        atomicAdd(&s_cnt[ei[NE + e0 + i] >> 8], 1);
    __syncthreads();

    // P2a: aligned global reservation (one atomic per nonempty bucket)
    for (int b = tid; b < BBUCK; b += 256) {
        int c = s_cnt[b];
        s_base[b] = c ? atomicAdd(&gcur[b], (c + 15) & ~15) : 0;
    }

    // P2b: exclusive scan of s_cnt -> s_ofs (chunks of 2)
    int v0 = 0, v1 = 0;
    {
        int i0 = tid * 2;
        if (i0     < BBUCK) v0 = s_cnt[i0];
        if (i0 + 1 < BBUCK) v1 = s_cnt[i0 + 1];
    }
    int csum = v0 + v1;
    s_sum[tid] = csum;
    __syncthreads();
    #pragma unroll
    for (int d = 1; d < 256; d <<= 1) {
        int t = (tid >= d) ? s_sum[tid - d] : 0;
        __syncthreads();
        s_sum[tid] += t;
        __syncthreads();
    }
    {
        int run = s_sum[tid] - csum;
        int i0 = tid * 2;
        if (i0     < BBUCK) { s_ofs[i0]     = run; run += v0; }
        if (i0 + 1 < BBUCK) { s_ofs[i0 + 1] = run; }
    }
    __syncthreads();

    // P3: scatter packed (local_dst<<17)|src into LDS staging
    for (int i = tid; i < cntE; i += 256) {
        int s = ei[e0 + i];
        int d = ei[NE + e0 + i];
        int b = d >> 8;
        int pos = atomicAdd(&s_ofs[b], 1);
        s_stage[pos] = ((unsigned int)(d & 255) << 17) | (unsigned int)s;
    }
    __syncthreads();

    // P4: coalesced copy-out, sentinel-padded to aligned reservation
    const int wid = tid >> 6, lane = tid & 63;
    for (int b = wid; b < BBUCK; b += 4) {
        int cnt = s_cnt[b];
        if (!cnt) continue;
        int res = (cnt + 15) & ~15;
        int rdo = s_ofs[b] - cnt;
        int gb  = s_base[b];
        int lim = min(res, b * NPB + NPB - gb);      // overflow clamp (never hits)
        for (int j = lane; j < lim; j += 64)
            gbin[(size_t)gb + j] = (j < cnt) ? s_stage[rdo + j] : SENT;
    }
}

// ===========================================================================
// Quarter-bucket counting sort v2: one block per 64-node gagg bucket (grid
// 1563, tiny LDS -> 8 blocks/CU).  Single filtered read of the parent
// 256-node bin run: append this quarter's words to a 10KB LDS buffer and
// histogram in the same pass; 64-entry scan; scatter to block-exclusive
// gsorted region (L2-local full-line writeback).  Output layout identical
// to r5 (goff[b*65], gsorted[b*NS]) -> gagg structure unchanged.
// ===========================================================================
__global__ __launch_bounds__(256) void k_sort(
    const unsigned int* __restrict__ gbin, const int* __restrict__ gcur,
    int* __restrict__ goff, int* __restrict__ gsorted)
{
    __shared__ unsigned int s_m[NS];                 // 10 KB
    __shared__ int s_cnt[CNODES], s_ofs[CNODES], s_loc[CNODES];
    __shared__ int s_n;
    const int tid = threadIdx.x;
    const int b64 = blockIdx.x;
    const int bkt = b64 >> 2, q = b64 & 3;
    const int nslots = min(gcur[bkt] - bkt * NPB, NPB);
    const unsigned int* run = gbin + (size_t)bkt * NPB;

    if (tid < CNODES) s_cnt[tid] = 0;
    if (tid == 0) s_n = 0;
    __syncthreads();

    // filtered append + histogram in one pass
    for (int i = tid; i < nslots; i += 256) {
        unsigned int w = run[i];
        if (w != SENT && (int)(w >> 23) == q) {
            int p = atomicAdd(&s_n, 1);
            if (p < NS) {                            // clamp (never hits)
                s_m[p] = w;
                atomicAdd(&s_cnt[(w >> 17) & 63], 1);
            }
        }
    }
    __syncthreads();

    // inclusive Hillis-Steele scan over 64 counters
    if (tid < CNODES) s_ofs[tid] = s_cnt[tid];
    __syncthreads();
    #pragma unroll
    for (int d = 1; d < CNODES; d <<= 1) {
        int t = (tid < CNODES && tid >= d) ? s_ofs[tid - d] : 0;
        __syncthreads();
        if (tid < CNODES) s_ofs[tid] += t;
        __syncthreads();
    }
    if (tid < CNODES) {
        int inc = s_ofs[tid];
        s_loc[tid] = inc - s_cnt[tid];               // exclusive
        goff[(size_t)b64 * 65 + tid + 1] = inc;
    }
    if (tid == 0) goff[(size_t)b64 * 65] = 0;
    __syncthreads();

    // scatter srcs into block-exclusive sorted region
    const int n = min(s_n, NS);
    int* dst = gsorted + (size_t)b64 * NS;
    for (int i = tid; i < n; i += 256) {
        unsigned int w = s_m[i];
        int pos = atomicAdd(&s_loc[(w >> 17) & 63], 1);
        dst[pos] = (int)(w & 0x1FFFFu);
    }
}

// ===========================================================================
// Fused gather-aggregate + GIN MLP, ATOMIC-FREE (r5 structure; 8-wide
// unrolled gather for deeper MLP on the latency-bound random reads).
// ===========================================================================
__global__ __launch_bounds__(256) void k_gagg1(
    const float* __restrict__ feat, const int* __restrict__ goff,
    const int* __restrict__ gsorted,
    const float* __restrict__ b1, const float* __restrict__ w2,
    const float* __restrict__ b2, const float* __restrict__ w3,
    float* __restrict__ outfeat)
{
    __shared__ float s_acc[CNODES * 16];
    __shared__ float s_w2[HID * HID], s_w3[HID * HID], s_b1[HID], s_b2[HID];
    __shared__ int s_off[CNODES + 1];
    const int tid = threadIdx.x;
    const int b   = blockIdx.x;

    s_w2[tid] = w2[tid];
    s_w3[tid] = w3[tid];
    if (tid < HID) { s_b1[tid] = b1[tid]; s_b2[tid] = b2[tid]; }
    if (tid < CNODES + 1) s_off[tid] = goff[(size_t)b * 65 + tid];
    __syncthreads();

    const int node = tid >> 2, q = tid & 3;
    const int* srcs = gsorted + (size_t)b * NS;
    const float4* pv = (const float4*)feat;
    float4 acc0 = make_float4(0.f, 0.f, 0.f, 0.f);
    float4 acc1 = make_float4(0.f, 0.f, 0.f, 0.f);
    int j = s_off[node];
    const int e = s_off[node + 1];
    for (; j + 7 < e; j += 8) {
        int s0 = srcs[j],     s1 = srcs[j + 1], s2 = srcs[j + 2], s3 = srcs[j + 3];
        int s4 = srcs[j + 4], s5 = srcs[j + 5], s6 = srcs[j + 6], s7 = srcs[j + 7];
        float4 v0 = pv[(size_t)s0 * 4 + q];
        float4 v1 = pv[(size_t)s1 * 4 + q];
        float4 v2 = pv[(size_t)s2 * 4 + q];
        float4 v3 = pv[(size_t)s3 * 4 + q];
        float4 v4 = pv[(size_t)s4 * 4 + q];
        float4 v5 = pv[(size_t)s5 * 4 + q];
        float4 v6 = pv[(size_t)s6 * 4 + q];
        float4 v7 = pv[(size_t)s7 * 4 + q];
        f4add(acc0, v0); f4add(acc1, v1); f4add(acc0, v2); f4add(acc1, v3);
        f4add(acc0, v4); f4add(acc1, v5); f4add(acc0, v6); f4add(acc1, v7);
    }
    for (; j + 3 < e; j += 4) {
        int s0 = srcs[j], s1 = srcs[j + 1], s2 = srcs[j + 2], s3 = srcs[j + 3];
        float4 v0 = pv[(size_t)s0 * 4 + q];
        float4 v1 = pv[(size_t)s1 * 4 + q];
        float4 v2 = pv[(size_t)s2 * 4 + q];
        float4 v3 = pv[(size_t)s3 * 4 + q];
        f4add(acc0, v0); f4add(acc1, v1); f4add(acc0, v2); f4add(acc1, v3);
    }
    for (; j < e; ++j)
        f4add(acc0, pv[(size_t)srcs[j] * 4 + q]);
    f4add(acc0, acc1);
    ((float4*)s_acc)[node * 4 + q] = acc0;
    __syncthreads();

    const int gn = b * CNODES + tid;
    if (tid < CNODES && gn < NN) {
        const float4* fr = (const float4*)(feat + (size_t)gn * HID);
        const float4* sa = (const float4*)(s_acc + tid * 16);
        float t[HID];
        #pragma unroll
        for (int i2 = 0; i2 < 4; ++i2) {
            float4 f = fr[i2], a = sa[i2];
            t[i2*4+0] = fmaxf(f.x + a.x + s_b1[i2*4+0], 0.f);
            t[i2*4+1] = fmaxf(f.y + a.y + s_b1[i2*4+1], 0.f);
            t[i2*4+2] = fmaxf(f.z + a.z + s_b1[i2*4+2], 0.f);
            t[i2*4+3] = fmaxf(f.w + a.w + s_b1[i2*4+3], 0.f);
        }
        float h[HID];
        #pragma unroll
        for (int i2 = 0; i2 < HID; ++i2) {
            float acc = s_b2[i2];
            #pragma unroll
            for (int jj = 0; jj < HID; ++jj) acc += t[jj] * s_w2[i2 * HID + jj];
            h[i2] = fmaxf(acc, 0.f);
        }
        float o[HID];
        #pragma unroll
        for (int i2 = 0; i2 < HID; ++i2) {
            float acc = 0.f;
            #pragma unroll
            for (int jj = 0; jj < HID; ++jj) acc += h[jj] * s_w3[i2 * HID + jj];
            o[i2] = acc;
        }
        float4* po = (float4*)(outfeat + (size_t)gn * HID);
        #pragma unroll
        for (int i2 = 0; i2 < 4; ++i2)
            po[i2] = make_float4(o[i2*4+0], o[i2*4+1], o[i2*4+2], o[i2*4+3]);
    }
}

__global__ __launch_bounds__(256) void k_gagg2(
    const float* __restrict__ feat, const int* __restrict__ goff,
    const int* __restrict__ gsorted,
    const float* __restrict__ b1, const float* __restrict__ w2,
    const float* __restrict__ b2, const float* __restrict__ row,
    const float* __restrict__ rob,
    float* __restrict__ out)
{
    __shared__ float s_acc[CNODES * 16];
    __shared__ float s_w2[HID * HID], s_b1[HID], s_b2[HID], s_ro[HID];
    __shared__ int s_off[CNODES + 1];
    const int tid = threadIdx.x;
    const int b   = blockIdx.x;

    s_w2[tid] = w2[tid];
    if (tid < HID) { s_b1[tid] = b1[tid]; s_b2[tid] = b2[tid]; s_ro[tid] = row[tid]; }
    if (tid < CNODES + 1) s_off[tid] = goff[(size_t)b * 65 + tid];
    __syncthreads();

    const int node = tid >> 2, q = tid & 3;
    const int* srcs = gsorted + (size_t)b * NS;
    const float4* pv = (const float4*)feat;
    float4 acc0 = make_float4(0.f, 0.f, 0.f, 0.f);
    float4 acc1 = make_float4(0.f, 0.f, 0.f, 0.f);
    int j = s_off[node];
    const int e = s_off[node + 1];
    for (; j + 7 < e; j += 8) {
        int s0 = srcs[j],     s1 = srcs[j + 1], s2 = srcs[j + 2], s3 = srcs[j + 3];
        int s4 = srcs[j + 4], s5 = srcs[j + 5], s6 = srcs[j + 6], s7 = srcs[j + 7];
        float4 v0 = pv[(size_t)s0 * 4 + q];
        float4 v1 = pv[(size_t)s1 * 4 + q];
        float4 v2 = pv[(size_t)s2 * 4 + q];
        float4 v3 = pv[(size_t)s3 * 4 + q];
        float4 v4 = pv[(size_t)s4 * 4 + q];
        float4 v5 = pv[(size_t)s5 * 4 + q];
        float4 v6 = pv[(size_t)s6 * 4 + q];
        float4 v7 = pv[(size_t)s7 * 4 + q];
        f4add(acc0, v0); f4add(acc1, v1); f4add(acc0, v2); f4add(acc1, v3);
        f4add(acc0, v4); f4add(acc1, v5); f4add(acc0, v6); f4add(acc1, v7);
    }
    for (; j + 3 < e; j += 4) {
        int s0 = srcs[j], s1 = srcs[j + 1], s2 = srcs[j + 2], s3 = srcs[j + 3];
        float4 v0 = pv[(size_t)s0 * 4 + q];
        float4 v1 = pv[(size_t)s1 * 4 + q];
        float4 v2 = pv[(size_t)s2 * 4 + q];
        float4 v3 = pv[(size_t)s3 * 4 + q];
        f4add(acc0, v0); f4add(acc1, v1); f4add(acc0, v2); f4add(acc1, v3);
    }
    for (; j < e; ++j)
        f4add(acc0, pv[(size_t)srcs[j] * 4 + q]);
    f4add(acc0, acc1);
    ((float4*)s_acc)[node * 4 + q] = acc0;
    __syncthreads();

    const int gn = b * CNODES + tid;
    if (tid < CNODES && gn < NN) {
        const float4* fr = (const float4*)(feat + (size_t)gn * HID);
        const float4* sa = (const float4*)(s_acc + tid * 16);
        float t[HID];
        #pragma unroll
        for (int i2 = 0; i2 < 4; ++i2) {
            float4 f = fr[i2], a = sa[i2];
            t[i2*4+0] = fmaxf(f.x + a.x + s_b1[i2*4+0], 0.f);
            t[i2*4+1] = fmaxf(f.y + a.y + s_b1[i2*4+1], 0.f);
            t[i2*4+2] = fmaxf(f.z + a.z + s_b1[i2*4+2], 0.f);
            t[i2*4+3] = fmaxf(f.w + a.w + s_b1[i2*4+3], 0.f);
        }
        float res = rob[0];
        #pragma unroll
        for (int i2 = 0; i2 < HID; ++i2) {
            float acc = s_b2[i2];
            #pragma unroll
            for (int jj = 0; jj < HID; ++jj) acc += t[jj] * s_w2[i2 * HID + jj];
            res += acc * s_ro[i2];
        }
        out[gn] = res;
    }
}

// ===========================================================================
// FALLBACK PATH kernels (workspace too small): per-node embed + atomic scatter
// ===========================================================================
__global__ __launch_bounds__(256) void k_embed(
    const float* __restrict__ x,
    const float* __restrict__ conv_w, const float* __restrict__ conv_b,
    const float* __restrict__ fc_w,   const float* __restrict__ fc_b,
    const float* __restrict__ g1w1,
    float* __restrict__ p1)
{
    __shared__ float s_x[4][TL];
    __shared__ float s_h[4][FLAT + 3];
    __shared__ float s_e[4][EMB];

    const int w    = threadIdx.x >> 6;
    const int lane = threadIdx.x & 63;
    const int node = blockIdx.x * 4 + w;

    const float2* xr = (const float2*)(x + (size_t)node * TL);
    float2 v = xr[lane];
    s_x[w][lane * 2 + 0] = v.x;
    s_x[w][lane * 2 + 1] = v.y;
    __syncthreads();

    for (int o = lane; o < FLAT; o += 64) {
        int c = o / CL;
        int t = o - c * CL;
        float acc = conv_b[c];
        #pragma unroll
        for (int k = 0; k < KW; ++k)
            acc += s_x[w][t * ST + k] * conv_w[c * KW + k];
        s_h[w][o] = fmaxf(acc, 0.f);
    }
    __syncthreads();

    if (lane < EMB) {
        float acc = fc_b[lane];
        const float* wr = fc_w + lane * FLAT;
        for (int j = 0; j < FLAT; ++j)
            acc += s_h[w][j] * wr[j];
        s_e[w][lane] = acc;
    }
    __syncthreads();

    if (lane < HID) {
        float acc = 0.f;
        const float* wr = g1w1 + lane * EMB;
        #pragma unroll
        for (int j = 0; j < EMB; ++j)
            acc += s_e[w][j] * wr[j];
        p1[(size_t)node * HID + lane] = acc;
    }
}

__global__ __launch_bounds__(256) void k_scatter(
    const float* __restrict__ p, const int* __restrict__ ei,
    float* __restrict__ agg)
{
    long long t = (long long)blockIdx.x * 256 + threadIdx.x;
    int e = (int)(t >> 4);
    int k = (int)(t & 15);
    if (e >= NE) return;
    int src = ei[e];
    int dst = ei[NE + e];
    float v = p[(size_t)src * HID + k];
    atomicAdd(agg + (size_t)dst * HID + k, v);
}

__global__ __launch_bounds__(256) void k_mlp1(
    const float* __restrict__ p1, const float* __restrict__ agg,
    const float* __restrict__ b1, const float* __restrict__ w2,
    const float* __restrict__ b2, const float* __restrict__ w3,
    float* __restrict__ p2)
{
    __shared__ float s_w2[HID * HID], s_w3[HID * HID], s_b1[HID], s_b2[HID];
    int tid = threadIdx.x;
    s_w2[tid] = w2[tid];
    s_w3[tid] = w3[tid];
    if (tid < HID) { s_b1[tid] = b1[tid]; s_b2[tid] = b2[tid]; }
    __syncthreads();

    int n = blockIdx.x * 256 + tid;
    if (n >= NN) return;

    float t[HID], h[HID];
    const float4* pa = (const float4*)(p1  + (size_t)n * HID);
    const float4* pb = (const float4*)(agg + (size_t)n * HID);
    #pragma unroll
    for (int i = 0; i < 4; ++i) {
        float4 a = pa[i], b = pb[i];
        t[i*4+0] = fmaxf(a.x + b.x + s_b1[i*4+0], 0.f);
        t[i*4+1] = fmaxf(a.y + b.y + s_b1[i*4+1], 0.f);
        t[i*4+2] = fmaxf(a.z + b.z + s_b1[i*4+2], 0.f);
        t[i*4+3] = fmaxf(a.w + b.w + s_b1[i*4+3], 0.f);
    }
    #pragma unroll
    for (int i = 0; i < HID; ++i) {
        float acc = s_b2[i];
        #pragma unroll
        for (int j = 0; j < HID; ++j) acc += t[j] * s_w2[i * HID + j];
        h[i] = fmaxf(acc, 0.f);
    }
    float o[HID];
    #pragma unroll
    for (int i = 0; i < HID; ++i) {
        float acc = 0.f;
        #pragma unroll
        for (int j = 0; j < HID; ++j) acc += h[j] * s_w3[i * HID + j];
        o[i] = acc;
    }
    float4* po = (float4*)(p2 + (size_t)n * HID);
    #pragma unroll
    for (int i = 0; i < 4; ++i)
        po[i] = make_float4(o[i*4+0], o[i*4+1], o[i*4+2], o[i*4+3]);
}

__global__ __launch_bounds__(256) void k_final(
    const float* __restrict__ p2, const float* __restrict__ agg2,
    const float* __restrict__ b1, const float* __restrict__ w2,
    const float* __restrict__ b2, const float* __restrict__ row,
    const float* __restrict__ rob,
    float* __restrict__ out)
{
    __shared__ float s_w2[HID * HID], s_b1[HID], s_b2[HID], s_ro[HID];
    int tid = threadIdx.x;
    s_w2[tid] = w2[tid];
    if (tid < HID) { s_b1[tid] = b1[tid]; s_b2[tid] = b2[tid]; s_ro[tid] = row[tid]; }
    __syncthreads();

    int n = blockIdx.x * 256 + tid;
    if (n >= NN) return;

    float t[HID];
    const float4* pa = (const float4*)(p2   + (size_t)n * HID);
    const float4* pb = (const float4*)(agg2 + (size_t)n * HID);
    #pragma unroll
    for (int i = 0; i < 4; ++i) {
        float4 a = pa[i], b = pb[i];
        t[i*4+0] = fmaxf(a.x + b.x + s_b1[i*4+0], 0.f);
        t[i*4+1] = fmaxf(a.y + b.y + s_b1[i*4+1], 0.f);
        t[i*4+2] = fmaxf(a.z + b.z + s_b1[i*4+2], 0.f);
        t[i*4+3] = fmaxf(a.w + b.w + s_b1[i*4+3], 0.f);
    }
    float res = rob[0];
    #pragma unroll
    for (int i = 0; i < HID; ++i) {
        float acc = s_b2[i];
        #pragma unroll
        for (int j = 0; j < HID; ++j) acc += t[j] * s_w2[i * HID + j];
        res += acc * s_ro[i];
    }
    out[n] = res;
}

// ===========================================================================
extern "C" void kernel_launch(void* const* d_in, const int* in_sizes, int n_in,
                              void* d_out, int out_size, void* d_ws, size_t ws_size,
                              hipStream_t stream)
{
    const float* x      = (const float*)d_in[0];
    const int*   ei     = (const int*)  d_in[1];
    const float* conv_w = (const float*)d_in[2];
    const float* conv_b = (const float*)d_in[3];
    const float* fc_w   = (const float*)d_in[4];
    const float* fc_b   = (const float*)d_in[5];
    const float* g1w1   = (const float*)d_in[6];
    const float* g1b1   = (const float*)d_in[7];
    const float* g1w2   = (const float*)d_in[8];
    const float* g1b2   = (const float*)d_in[9];
    const float* g2w1   = (const float*)d_in[10];
    const float* g2b1   = (const float*)d_in[11];
    const float* g2w2   = (const float*)d_in[12];
    const float* g2b2   = (const float*)d_in[13];
    const float* ro_w   = (const float*)d_in[14];
    const float* ro_b   = (const float*)d_in[15];
    float* out = (float*)d_out;

    // workspace layout:
    //   A       [NN*HID] f32        p1 (projected features)
    //   B       [NN*HID] f32        p2 (layer-2 projected features)
    //   wcT     [FLAT*HID] f32      combined fc+g1w1 weight
    //   bc      [16] f32            combined bias
    //   gcur    [BBUCK] i32         bin cursors
    //   gbin    [BBUCK*NPB] u32     packed (local_dst<<17)|src per bin bucket
    //   goff    [NGB*65] i32        per-node offsets within gagg bucket
    //   gsorted [NGB*NS] i32        dst-sorted src ids per gagg bucket
    float* A    = (float*)d_ws;
    float* B    = A + (size_t)NN * HID;
    float* wcT  = B + (size_t)NN * HID;
    float* bc   = wcT + (size_t)FLAT * HID;
    int*   gcur = (int*)(bc + 16);
    unsigned int* gbin = (unsigned int*)(gcur + BBUCK);
    int*   goff    = (int*)(gbin + (size_t)BBUCK * NPB);
    int*   gsorted = goff + (size_t)NGB * 65;
    const size_t need = (size_t)((char*)(gsorted + (size_t)NGB * NS) - (char*)d_ws);

    if (ws_size >= need) {
        k_prep<<<1, 256, 0, stream>>>(g1w1, fc_w, fc_b, wcT, bc, gcur);
        k_convfc<<<NN / 32, 256, 0, stream>>>(x, conv_w, conv_b, wcT, bc, A);
        k_bin<<<NBIN, 256, 0, stream>>>(ei, gcur, gbin);
        k_sort<<<NGB, 256, 0, stream>>>(gbin, gcur, goff, gsorted);
        // GIN layer 1: atomic-free gather + MLP + layer-2 projection
        k_gagg1<<<NGB, 256, 0, stream>>>(A, goff, gsorted, g1b1, g1w2, g1b2,
                                         g2w1, B);
        // GIN layer 2: atomic-free gather + MLP + readout
        k_gagg2<<<NGB, 256, 0, stream>>>(B, goff, gsorted, g2b1, g2w2, g2b2,
                                         ro_w, ro_b, out);
    } else {
        // --- fallback: fused per-node embed + atomic scatter ---
        k_embed<<<NN / 4, 256, 0, stream>>>(x, conv_w, conv_b, fc_w, fc_b,
                                            g1w1, A);
        hipMemsetAsync(B, 0, (size_t)NN * HID * sizeof(float), stream);
        k_scatter<<<(int)(((long long)NE * HID) / 256), 256, 0, stream>>>(A, ei, B);
        k_mlp1<<<(NN + 255) / 256, 256, 0, stream>>>(A, B, g1b1, g1w2, g1b2,
                                                     g2w1, A);
        hipMemsetAsync(B, 0, (size_t)NN * HID * sizeof(float), stream);
        k_scatter<<<(int)(((long long)NE * HID) / 256), 256, 0, stream>>>(A, ei, B);
        k_final<<<(NN + 255) / 256, 256, 0, stream>>>(A, B, g2b1, g2w2, g2b2,
                                                      ro_w, ro_b, out);
    }
}

// Round 7
// 360.001 us; speedup vs baseline: 2.6202x; 1.0203x over previous
//
#include <hip/hip_runtime.h>

#define NN   100000
#define TL   128
#define OC   5
#define KW   7
#define ST   3
#define CL   41          // (128-7)/3+1
#define FLAT 205         // 5*41
#define EMB  32
#define HID  16
#define NE   3200000

#define CLP  44                  // per-channel padded conv length (4-aligned)
#define JP   220                 // OC*CLP, padded flat length
#define JB   55                  // JP/4 float4 blocks

#define BBUCK  391               // bin buckets (256 nodes each, dst>>8)
#define NPB    14336             // slots per bin bucket (mean fill ~12980, +16 sigma)
#define TILE   4096              // edges per k_bin block
#define NBIN   782               // ceil(NE/TILE)
#define CNODES 64                // nodes per gagg/sort bucket
#define NGB    1563              // ceil(NN/64)
#define NS     2560              // sorted-src capacity per 64-node bucket (mean 2048)
#define SENT   0xFFFFFFFFu       // sentinel slot (real words are < 2^26)

__device__ __forceinline__ void f4add(float4& a, const float4 v) {
    a.x += v.x; a.y += v.y; a.z += v.z; a.w += v.w;
}

// ===========================================================================
// Precompute combined weight wcTl = g1w1 @ fc_w, L-MAJOR and channel-padded:
// wcTl[l*JP + c*CLP + t] = sum_m g1w1[l,m]*fc_w[m, c*41+t]  (t<41; else 0).
// bc = g1w1 @ fc_b.  Also init per-bucket bin cursors gcur[b] = b*NPB.
// ===========================================================================
__global__ __launch_bounds__(256) void k_prep(
    const float* __restrict__ g1w1, const float* __restrict__ fc_w,
    const float* __restrict__ fc_b,
    float* __restrict__ wcTl, float* __restrict__ bc,
    int* __restrict__ gcur)
{
    int tid = threadIdx.x;
    for (int idx = tid; idx < HID * JP; idx += 256) {
        int l  = idx / JP;
        int jp = idx - l * JP;
        int c  = jp / CLP;
        int t  = jp - c * CLP;
        float s = 0.f;
        if (t < CL) {
            int j = c * CL + t;
            #pragma unroll
            for (int m = 0; m < EMB; ++m)
                s = fmaf(g1w1[l * EMB + m], fc_w[m * FLAT + j], s);
        }
        wcTl[idx] = s;
    }
    if (tid < HID) {
        float s = 0.f;
        #pragma unroll
        for (int m = 0; m < EMB; ++m)
            s = fmaf(g1w1[tid * EMB + m], fc_b[m], s);
        bc[tid] = s;
    }
    for (int b = tid; b < BBUCK; b += 256)
        gcur[b] = b * NPB;
}

// ===========================================================================
// Fused Conv1d+ReLU+FC(+g1w1), LDS-instruction-optimized:
//  - conv: thread computes 4 consecutive t for one (c,n): 16 shared-window
//    b32 reads / 4 outputs (vs 7/output), one ds_write_b128 to the
//    channel-padded s_h2[n][c*44+t] (pad slots written 0).
//  - FC: h read as ds_read_b128 (55/node, 16-lane broadcast, disjoint bank
//    groups), weights as float4 GLOBAL loads from l-major wcTl (VMEM pipe).
// Per-wave DS instructions ~245 vs ~630 before (was LDS-issue-bound).
// LDS = 16.2 + 27.5 KB -> 3 blocks/CU.
// ===========================================================================
__global__ __launch_bounds__(256) void k_convfc(
    const float* __restrict__ x,
    const float* __restrict__ conv_w, const float* __restrict__ conv_b,
    const float* __restrict__ wcTl,  const float* __restrict__ bc,
    float* __restrict__ p1)
{
    __shared__ float s_x[32 * 129 + 8];    // +8: tg=10 window over-read pad
    __shared__ float s_h2[32 * JP];
    const int tid = threadIdx.x;
    const long long n0 = (long long)blockIdx.x * 32;   // NN = 32*3125 exact

    // stage 32 x-rows: 1024 float4 loads, coalesced; row-padded LDS writes
    const float4* xv = (const float4*)(x + n0 * TL);
    #pragma unroll
    for (int c = 0; c < 4; ++c) {
        int f4  = c * 256 + tid;
        int row = f4 >> 5;
        int c4  = f4 & 31;
        float4 v = xv[f4];
        float* d = s_x + row * 129 + c4 * 4;
        d[0] = v.x; d[1] = v.y; d[2] = v.z; d[3] = v.w;
    }
    __syncthreads();

    // conv: 55 (c,tg) groups x 32 nodes; 4 outputs per item
    for (int i = tid; i < 55 * 32; i += 256) {
        int n  = i & 31;
        int ci = i >> 5;            // 0..54
        int c  = ci / 11;
        int tg = ci - c * 11;
        int t0 = tg * 4;
        const float* xr = s_x + n * 129 + t0 * ST;
        float xx[16];
        #pragma unroll
        for (int k = 0; k < 16; ++k) xx[k] = xr[k];
        const float* wr = conv_w + c * KW;
        float w0 = wr[0], w1 = wr[1], w2 = wr[2], w3 = wr[3],
              w4 = wr[4], w5 = wr[5], w6 = wr[6];
        float bb = conv_b[c];
        float4 r;
        r.x = fmaxf(bb + xx[0]*w0 + xx[1]*w1 + xx[2]*w2 + xx[3]*w3
                       + xx[4]*w4 + xx[5]*w5 + xx[6]*w6, 0.f);
        r.y = (t0 + 1 < CL)
            ? fmaxf(bb + xx[3]*w0 + xx[4]*w1 + xx[5]*w2 + xx[6]*w3
                       + xx[7]*w4 + xx[8]*w5 + xx[9]*w6, 0.f) : 0.f;
        r.z = (t0 + 2 < CL)
            ? fmaxf(bb + xx[6]*w0 + xx[7]*w1 + xx[8]*w2 + xx[9]*w3
                       + xx[10]*w4 + xx[11]*w5 + xx[12]*w6, 0.f) : 0.f;
        r.w = (t0 + 3 < CL)
            ? fmaxf(bb + xx[9]*w0 + xx[10]*w1 + xx[11]*w2 + xx[12]*w3
                       + xx[13]*w4 + xx[14]*w5 + xx[15]*w6, 0.f) : 0.f;
        *(float4*)(s_h2 + n * JP + c * CLP + t0) = r;
    }
    __syncthreads();

    // FC: thread = (l, n2) handling nodes n2 and n2+16
    const int l  = tid & 15;
    const int n2 = tid >> 4;
    float a0 = bc[l];
    float a1 = a0;
    const float4* wl = (const float4*)(wcTl + l * JP);
    const float4* h0 = (const float4*)(s_h2 + n2 * JP);
    const float4* h1 = (const float4*)(s_h2 + (n2 + 16) * JP);
    #pragma unroll 5
    for (int jb = 0; jb < JB; ++jb) {
        float4 w = wl[jb];
        float4 p = h0[jb];
        float4 q = h1[jb];
        a0 = fmaf(p.x, w.x, fmaf(p.y, w.y, fmaf(p.z, w.z, fmaf(p.w, w.w, a0))));
        a1 = fmaf(q.x, w.x, fmaf(q.y, w.y, fmaf(q.z, w.z, fmaf(q.w, w.w, a1))));
    }
    p1[(n0 + n2)      * HID + l] = a0;
    p1[(n0 + n2 + 16) * HID + l] = a1;
}

// ===========================================================================
// LDS-staged bucket binning v2 (unchanged, verified r6).
// ===========================================================================
__global__ __launch_bounds__(256) void k_bin(
    const int* __restrict__ ei, int* __restrict__ gcur,
    unsigned int* __restrict__ gbin)
{
    __shared__ unsigned int s_stage[TILE];                 // 16 KB
    __shared__ int s_cnt[BBUCK], s_ofs[BBUCK], s_base[BBUCK];  // 4.7 KB
    __shared__ int s_sum[256];

    const int tid = threadIdx.x;
    const int e0  = blockIdx.x * TILE;
    const int cntE = min(TILE, NE - e0);

    for (int b = tid; b < BBUCK; b += 256) s_cnt[b] = 0;
    __syncthreads();

    // P1: histogram over 391 buckets
    for (int i = tid; i < cntE; i += 256)
        atomicAdd(&s_cnt[ei[NE + e0 + i] >> 8], 1);
    __syncthreads();

    // P2a: aligned global reservation (one atomic per nonempty bucket)
    for (int b = tid; b < BBUCK; b += 256) {
        int c = s_cnt[b];
        s_base[b] = c ? atomicAdd(&gcur[b], (c + 15) & ~15) : 0;
    }

    // P2b: exclusive scan of s_cnt -> s_ofs (chunks of 2)
    int v0 = 0, v1 = 0;
    {
        int i0 = tid * 2;
        if (i0     < BBUCK) v0 = s_cnt[i0];
        if (i0 + 1 < BBUCK) v1 = s_cnt[i0 + 1];
    }
    int csum = v0 + v1;
    s_sum[tid] = csum;
    __syncthreads();
    #pragma unroll
    for (int d = 1; d < 256; d <<= 1) {
        int t = (tid >= d) ? s_sum[tid - d] : 0;
        __syncthreads();
        s_sum[tid] += t;
        __syncthreads();
    }
    {
        int run = s_sum[tid] - csum;
        int i0 = tid * 2;
        if (i0     < BBUCK) { s_ofs[i0]     = run; run += v0; }
        if (i0 + 1 < BBUCK) { s_ofs[i0 + 1] = run; }
    }
    __syncthreads();

    // P3: scatter packed (local_dst<<17)|src into LDS staging
    for (int i = tid; i < cntE; i += 256) {
        int s = ei[e0 + i];
        int d = ei[NE + e0 + i];
        int b = d >> 8;
        int pos = atomicAdd(&s_ofs[b], 1);
        s_stage[pos] = ((unsigned int)(d & 255) << 17) | (unsigned int)s;
    }
    __syncthreads();

    // P4: coalesced copy-out, sentinel-padded to aligned reservation
    const int wid = tid >> 6, lane = tid & 63;
    for (int b = wid; b < BBUCK; b += 4) {
        int cnt = s_cnt[b];
        if (!cnt) continue;
        int res = (cnt + 15) & ~15;
        int rdo = s_ofs[b] - cnt;
        int gb  = s_base[b];
        int lim = min(res, b * NPB + NPB - gb);      // overflow clamp (never hits)
        for (int j = lane; j < lim; j += 64)
            gbin[(size_t)gb + j] = (j < cnt) ? s_stage[rdo + j] : SENT;
    }
}

// ===========================================================================
// Quarter-bucket counting sort v2 (unchanged, verified r6).
// ===========================================================================
__global__ __launch_bounds__(256) void k_sort(
    const unsigned int* __restrict__ gbin, const int* __restrict__ gcur,
    int* __restrict__ goff, int* __restrict__ gsorted)
{
    __shared__ unsigned int s_m[NS];                 // 10 KB
    __shared__ int s_cnt[CNODES], s_ofs[CNODES], s_loc[CNODES];
    __shared__ int s_n;
    const int tid = threadIdx.x;
    const int b64 = blockIdx.x;
    const int bkt = b64 >> 2, q = b64 & 3;
    const int nslots = min(gcur[bkt] - bkt * NPB, NPB);
    const unsigned int* run = gbin + (size_t)bkt * NPB;

    if (tid < CNODES) s_cnt[tid] = 0;
    if (tid == 0) s_n = 0;
    __syncthreads();

    // filtered append + histogram in one pass
    for (int i = tid; i < nslots; i += 256) {
        unsigned int w = run[i];
        if (w != SENT && (int)(w >> 23) == q) {
            int p = atomicAdd(&s_n, 1);
            if (p < NS) {                            // clamp (never hits)
                s_m[p] = w;
                atomicAdd(&s_cnt[(w >> 17) & 63], 1);
            }
        }
    }
    __syncthreads();

    // inclusive Hillis-Steele scan over 64 counters
    if (tid < CNODES) s_ofs[tid] = s_cnt[tid];
    __syncthreads();
    #pragma unroll
    for (int d = 1; d < CNODES; d <<= 1) {
        int t = (tid < CNODES && tid >= d) ? s_ofs[tid - d] : 0;
        __syncthreads();
        if (tid < CNODES) s_ofs[tid] += t;
        __syncthreads();
    }
    if (tid < CNODES) {
        int inc = s_ofs[tid];
        s_loc[tid] = inc - s_cnt[tid];               // exclusive
        goff[(size_t)b64 * 65 + tid + 1] = inc;
    }
    if (tid == 0) goff[(size_t)b64 * 65] = 0;
    __syncthreads();

    // scatter srcs into block-exclusive sorted region
    const int n = min(s_n, NS);
    int* dst = gsorted + (size_t)b64 * NS;
    for (int i = tid; i < n; i += 256) {
        unsigned int w = s_m[i];
        int pos = atomicAdd(&s_loc[(w >> 17) & 63], 1);
        dst[pos] = (int)(w & 0x1FFFFu);
    }
}

// ===========================================================================
// Fused gather-aggregate + GIN MLP, ATOMIC-FREE (unchanged, verified r6).
// ===========================================================================
__global__ __launch_bounds__(256) void k_gagg1(
    const float* __restrict__ feat, const int* __restrict__ goff,
    const int* __restrict__ gsorted,
    const float* __restrict__ b1, const float* __restrict__ w2,
    const float* __restrict__ b2, const float* __restrict__ w3,
    float* __restrict__ outfeat)
{
    __shared__ float s_acc[CNODES * 16];
    __shared__ float s_w2[HID * HID], s_w3[HID * HID], s_b1[HID], s_b2[HID];
    __shared__ int s_off[CNODES + 1];
    const int tid = threadIdx.x;
    const int b   = blockIdx.x;

    s_w2[tid] = w2[tid];
    s_w3[tid] = w3[tid];
    if (tid < HID) { s_b1[tid] = b1[tid]; s_b2[tid] = b2[tid]; }
    if (tid < CNODES + 1) s_off[tid] = goff[(size_t)b * 65 + tid];
    __syncthreads();

    const int node = tid >> 2, q = tid & 3;
    const int* srcs = gsorted + (size_t)b * NS;
    const float4* pv = (const float4*)feat;
    float4 acc0 = make_float4(0.f, 0.f, 0.f, 0.f);
    float4 acc1 = make_float4(0.f, 0.f, 0.f, 0.f);
    int j = s_off[node];
    const int e = s_off[node + 1];
    for (; j + 7 < e; j += 8) {
        int s0 = srcs[j],     s1 = srcs[j + 1], s2 = srcs[j + 2], s3 = srcs[j + 3];
        int s4 = srcs[j + 4], s5 = srcs[j + 5], s6 = srcs[j + 6], s7 = srcs[j + 7];
        float4 v0 = pv[(size_t)s0 * 4 + q];
        float4 v1 = pv[(size_t)s1 * 4 + q];
        float4 v2 = pv[(size_t)s2 * 4 + q];
        float4 v3 = pv[(size_t)s3 * 4 + q];
        float4 v4 = pv[(size_t)s4 * 4 + q];
        float4 v5 = pv[(size_t)s5 * 4 + q];
        float4 v6 = pv[(size_t)s6 * 4 + q];
        float4 v7 = pv[(size_t)s7 * 4 + q];
        f4add(acc0, v0); f4add(acc1, v1); f4add(acc0, v2); f4add(acc1, v3);
        f4add(acc0, v4); f4add(acc1, v5); f4add(acc0, v6); f4add(acc1, v7);
    }
    for (; j + 3 < e; j += 4) {
        int s0 = srcs[j], s1 = srcs[j + 1], s2 = srcs[j + 2], s3 = srcs[j + 3];
        float4 v0 = pv[(size_t)s0 * 4 + q];
        float4 v1 = pv[(size_t)s1 * 4 + q];
        float4 v2 = pv[(size_t)s2 * 4 + q];
        float4 v3 = pv[(size_t)s3 * 4 + q];
        f4add(acc0, v0); f4add(acc1, v1); f4add(acc0, v2); f4add(acc1, v3);
    }
    for (; j < e; ++j)
        f4add(acc0, pv[(size_t)srcs[j] * 4 + q]);
    f4add(acc0, acc1);
    ((float4*)s_acc)[node * 4 + q] = acc0;
    __syncthreads();

    const int gn = b * CNODES + tid;
    if (tid < CNODES && gn < NN) {
        const float4* fr = (const float4*)(feat + (size_t)gn * HID);
        const float4* sa = (const float4*)(s_acc + tid * 16);
        float t[HID];
        #pragma unroll
        for (int i2 = 0; i2 < 4; ++i2) {
            float4 f = fr[i2], a = sa[i2];
            t[i2*4+0] = fmaxf(f.x + a.x + s_b1[i2*4+0], 0.f);
            t[i2*4+1] = fmaxf(f.y + a.y + s_b1[i2*4+1], 0.f);
            t[i2*4+2] = fmaxf(f.z + a.z + s_b1[i2*4+2], 0.f);
            t[i2*4+3] = fmaxf(f.w + a.w + s_b1[i2*4+3], 0.f);
        }
        float h[HID];
        #pragma unroll
        for (int i2 = 0; i2 < HID; ++i2) {
            float acc = s_b2[i2];
            #pragma unroll
            for (int jj = 0; jj < HID; ++jj) acc += t[jj] * s_w2[i2 * HID + jj];
            h[i2] = fmaxf(acc, 0.f);
        }
        float o[HID];
        #pragma unroll
        for (int i2 = 0; i2 < HID; ++i2) {
            float acc = 0.f;
            #pragma unroll
            for (int jj = 0; jj < HID; ++jj) acc += h[jj] * s_w3[i2 * HID + jj];
            o[i2] = acc;
        }
        float4* po = (float4*)(outfeat + (size_t)gn * HID);
        #pragma unroll
        for (int i2 = 0; i2 < 4; ++i2)
            po[i2] = make_float4(o[i2*4+0], o[i2*4+1], o[i2*4+2], o[i2*4+3]);
    }
}

__global__ __launch_bounds__(256) void k_gagg2(
    const float* __restrict__ feat, const int* __restrict__ goff,
    const int* __restrict__ gsorted,
    const float* __restrict__ b1, const float* __restrict__ w2,
    const float* __restrict__ b2, const float* __restrict__ row,
    const float* __restrict__ rob,
    float* __restrict__ out)
{
    __shared__ float s_acc[CNODES * 16];
    __shared__ float s_w2[HID * HID], s_b1[HID], s_b2[HID], s_ro[HID];
    __shared__ int s_off[CNODES + 1];
    const int tid = threadIdx.x;
    const int b   = blockIdx.x;

    s_w2[tid] = w2[tid];
    if (tid < HID) { s_b1[tid] = b1[tid]; s_b2[tid] = b2[tid]; s_ro[tid] = row[tid]; }
    if (tid < CNODES + 1) s_off[tid] = goff[(size_t)b * 65 + tid];
    __syncthreads();

    const int node = tid >> 2, q = tid & 3;
    const int* srcs = gsorted + (size_t)b * NS;
    const float4* pv = (const float4*)feat;
    float4 acc0 = make_float4(0.f, 0.f, 0.f, 0.f);
    float4 acc1 = make_float4(0.f, 0.f, 0.f, 0.f);
    int j = s_off[node];
    const int e = s_off[node + 1];
    for (; j + 7 < e; j += 8) {
        int s0 = srcs[j],     s1 = srcs[j + 1], s2 = srcs[j + 2], s3 = srcs[j + 3];
        int s4 = srcs[j + 4], s5 = srcs[j + 5], s6 = srcs[j + 6], s7 = srcs[j + 7];
        float4 v0 = pv[(size_t)s0 * 4 + q];
        float4 v1 = pv[(size_t)s1 * 4 + q];
        float4 v2 = pv[(size_t)s2 * 4 + q];
        float4 v3 = pv[(size_t)s3 * 4 + q];
        float4 v4 = pv[(size_t)s4 * 4 + q];
        float4 v5 = pv[(size_t)s5 * 4 + q];
        float4 v6 = pv[(size_t)s6 * 4 + q];
        float4 v7 = pv[(size_t)s7 * 4 + q];
        f4add(acc0, v0); f4add(acc1, v1); f4add(acc0, v2); f4add(acc1, v3);
        f4add(acc0, v4); f4add(acc1, v5); f4add(acc0, v6); f4add(acc1, v7);
    }
    for (; j + 3 < e; j += 4) {
        int s0 = srcs[j], s1 = srcs[j + 1], s2 = srcs[j + 2], s3 = srcs[j + 3];
        float4 v0 = pv[(size_t)s0 * 4 + q];
        float4 v1 = pv[(size_t)s1 * 4 + q];
        float4 v2 = pv[(size_t)s2 * 4 + q];
        float4 v3 = pv[(size_t)s3 * 4 + q];
        f4add(acc0, v0); f4add(acc1, v1); f4add(acc0, v2); f4add(acc1, v3);
    }
    for (; j < e; ++j)
        f4add(acc0, pv[(size_t)srcs[j] * 4 + q]);
    f4add(acc0, acc1);
    ((float4*)s_acc)[node * 4 + q] = acc0;
    __syncthreads();

    const int gn = b * CNODES + tid;
    if (tid < CNODES && gn < NN) {
        const float4* fr = (const float4*)(feat + (size_t)gn * HID);
        const float4* sa = (const float4*)(s_acc + tid * 16);
        float t[HID];
        #pragma unroll
        for (int i2 = 0; i2 < 4; ++i2) {
            float4 f = fr[i2], a = sa[i2];
            t[i2*4+0] = fmaxf(f.x + a.x + s_b1[i2*4+0], 0.f);
            t[i2*4+1] = fmaxf(f.y + a.y + s_b1[i2*4+1], 0.f);
            t[i2*4+2] = fmaxf(f.z + a.z + s_b1[i2*4+2], 0.f);
            t[i2*4+3] = fmaxf(f.w + a.w + s_b1[i2*4+3], 0.f);
        }
        float res = rob[0];
        #pragma unroll
        for (int i2 = 0; i2 < HID; ++i2) {
            float acc = s_b2[i2];
            #pragma unroll
            for (int jj = 0; jj < HID; ++jj) acc += t[jj] * s_w2[i2 * HID + jj];
            res += acc * s_ro[i2];
        }
        out[gn] = res;
    }
}

// ===========================================================================
// FALLBACK PATH kernels (workspace too small): per-node embed + atomic scatter
// ===========================================================================
__global__ __launch_bounds__(256) void k_embed(
    const float* __restrict__ x,
    const float* __restrict__ conv_w, const float* __restrict__ conv_b,
    const float* __restrict__ fc_w,   const float* __restrict__ fc_b,
    const float* __restrict__ g1w1,
    float* __restrict__ p1)
{
    __shared__ float s_x[4][TL];
    __shared__ float s_h[4][FLAT + 3];
    __shared__ float s_e[4][EMB];

    const int w    = threadIdx.x >> 6;
    const int lane = threadIdx.x & 63;
    const int node = blockIdx.x * 4 + w;

    const float2* xr = (const float2*)(x + (size_t)node * TL);
    float2 v = xr[lane];
    s_x[w][lane * 2 + 0] = v.x;
    s_x[w][lane * 2 + 1] = v.y;
    __syncthreads();

    for (int o = lane; o < FLAT; o += 64) {
        int c = o / CL;
        int t = o - c * CL;
        float acc = conv_b[c];
        #pragma unroll
        for (int k = 0; k < KW; ++k)
            acc += s_x[w][t * ST + k] * conv_w[c * KW + k];
        s_h[w][o] = fmaxf(acc, 0.f);
    }
    __syncthreads();

    if (lane < EMB) {
        float acc = fc_b[lane];
        const float* wr = fc_w + lane * FLAT;
        for (int j = 0; j < FLAT; ++j)
            acc += s_h[w][j] * wr[j];
        s_e[w][lane] = acc;
    }
    __syncthreads();

    if (lane < HID) {
        float acc = 0.f;
        const float* wr = g1w1 + lane * EMB;
        #pragma unroll
        for (int j = 0; j < EMB; ++j)
            acc += s_e[w][j] * wr[j];
        p1[(size_t)node * HID + lane] = acc;
    }
}

__global__ __launch_bounds__(256) void k_scatter(
    const float* __restrict__ p, const int* __restrict__ ei,
    float* __restrict__ agg)
{
    long long t = (long long)blockIdx.x * 256 + threadIdx.x;
    int e = (int)(t >> 4);
    int k = (int)(t & 15);
    if (e >= NE) return;
    int src = ei[e];
    int dst = ei[NE + e];
    float v = p[(size_t)src * HID + k];
    atomicAdd(agg + (size_t)dst * HID + k, v);
}

__global__ __launch_bounds__(256) void k_mlp1(
    const float* __restrict__ p1, const float* __restrict__ agg,
    const float* __restrict__ b1, const float* __restrict__ w2,
    const float* __restrict__ b2, const float* __restrict__ w3,
    float* __restrict__ p2)
{
    __shared__ float s_w2[HID * HID], s_w3[HID * HID], s_b1[HID], s_b2[HID];
    int tid = threadIdx.x;
    s_w2[tid] = w2[tid];
    s_w3[tid] = w3[tid];
    if (tid < HID) { s_b1[tid] = b1[tid]; s_b2[tid] = b2[tid]; }
    __syncthreads();

    int n = blockIdx.x * 256 + tid;
    if (n >= NN) return;

    float t[HID], h[HID];
    const float4* pa = (const float4*)(p1  + (size_t)n * HID);
    const float4* pb = (const float4*)(agg + (size_t)n * HID);
    #pragma unroll
    for (int i = 0; i < 4; ++i) {
        float4 a = pa[i], b = pb[i];
        t[i*4+0] = fmaxf(a.x + b.x + s_b1[i*4+0], 0.f);
        t[i*4+1] = fmaxf(a.y + b.y + s_b1[i*4+1], 0.f);
        t[i*4+2] = fmaxf(a.z + b.z + s_b1[i*4+2], 0.f);
        t[i*4+3] = fmaxf(a.w + b.w + s_b1[i*4+3], 0.f);
    }
    #pragma unroll
    for (int i = 0; i < HID; ++i) {
        float acc = s_b2[i];
        #pragma unroll
        for (int j = 0; j < HID; ++j) acc += t[j] * s_w2[i * HID + j];
        h[i] = fmaxf(acc, 0.f);
    }
    float o[HID];
    #pragma unroll
    for (int i = 0; i < HID; ++i) {
        float acc = 0.f;
        #pragma unroll
        for (int j = 0; j < HID; ++j) acc += h[j] * s_w3[i * HID + j];
        o[i] = acc;
    }
    float4* po = (float4*)(p2 + (size_t)n * HID);
    #pragma unroll
    for (int i = 0; i < 4; ++i)
        po[i] = make_float4(o[i*4+0], o[i*4+1], o[i*4+2], o[i*4+3]);
}

__global__ __launch_bounds__(256) void k_final(
    const float* __restrict__ p2, const float* __restrict__ agg2,
    const float* __restrict__ b1, const float* __restrict__ w2,
    const float* __restrict__ b2, const float* __restrict__ row,
    const float* __restrict__ rob,
    float* __restrict__ out)
{
    __shared__ float s_w2[HID * HID], s_b1[HID], s_b2[HID], s_ro[HID];
    int tid = threadIdx.x;
    s_w2[tid] = w2[tid];
    if (tid < HID) { s_b1[tid] = b1[tid]; s_b2[tid] = b2[tid]; s_ro[tid] = row[tid]; }
    __syncthreads();

    int n = blockIdx.x * 256 + tid;
    if (n >= NN) return;

    float t[HID];
    const float4* pa = (const float4*)(p2   + (size_t)n * HID);
    const float4* pb = (const float4*)(agg2 + (size_t)n * HID);
    #pragma unroll
    for (int i = 0; i < 4; ++i) {
        float4 a = pa[i], b = pb[i];
        t[i*4+0] = fmaxf(a.x + b.x + s_b1[i*4+0], 0.f);
        t[i*4+1] = fmaxf(a.y + b.y + s_b1[i*4+1], 0.f);
        t[i*4+2] = fmaxf(a.z + b.z + s_b1[i*4+2], 0.f);
        t[i*4+3] = fmaxf(a.w + b.w + s_b1[i*4+3], 0.f);
    }
    float res = rob[0];
    #pragma unroll
    for (int i = 0; i < HID; ++i) {
        float acc = s_b2[i];
        #pragma unroll
        for (int j = 0; j < HID; ++j) acc += t[j] * s_w2[i * HID + j];
        res += acc * s_ro[i];
    }
    out[n] = res;
}

// ===========================================================================
extern "C" void kernel_launch(void* const* d_in, const int* in_sizes, int n_in,
                              void* d_out, int out_size, void* d_ws, size_t ws_size,
                              hipStream_t stream)
{
    const float* x      = (const float*)d_in[0];
    const int*   ei     = (const int*)  d_in[1];
    const float* conv_w = (const float*)d_in[2];
    const float* conv_b = (const float*)d_in[3];
    const float* fc_w   = (const float*)d_in[4];
    const float* fc_b   = (const float*)d_in[5];
    const float* g1w1   = (const float*)d_in[6];
    const float* g1b1   = (const float*)d_in[7];
    const float* g1w2   = (const float*)d_in[8];
    const float* g1b2   = (const float*)d_in[9];
    const float* g2w1   = (const float*)d_in[10];
    const float* g2b1   = (const float*)d_in[11];
    const float* g2w2   = (const float*)d_in[12];
    const float* g2b2   = (const float*)d_in[13];
    const float* ro_w   = (const float*)d_in[14];
    const float* ro_b   = (const float*)d_in[15];
    float* out = (float*)d_out;

    // workspace layout:
    //   A       [NN*HID] f32        p1 (projected features)
    //   B       [NN*HID] f32        p2 (layer-2 projected features)
    //   wcTl    [HID*JP] f32        combined fc+g1w1 weight, l-major padded
    //   bc      [16] f32            combined bias
    //   gcur    [BBUCK] i32         bin cursors
    //   gbin    [BBUCK*NPB] u32     packed (local_dst<<17)|src per bin bucket
    //   goff    [NGB*65] i32        per-node offsets within gagg bucket
    //   gsorted [NGB*NS] i32        dst-sorted src ids per gagg bucket
    float* A    = (float*)d_ws;
    float* B    = A + (size_t)NN * HID;
    float* wcTl = B + (size_t)NN * HID;
    float* bc   = wcTl + (size_t)HID * JP;
    int*   gcur = (int*)(bc + 16);
    unsigned int* gbin = (unsigned int*)(gcur + BBUCK);
    int*   goff    = (int*)(gbin + (size_t)BBUCK * NPB);
    int*   gsorted = goff + (size_t)NGB * 65;
    const size_t need = (size_t)((char*)(gsorted + (size_t)NGB * NS) - (char*)d_ws);

    if (ws_size >= need) {
        k_prep<<<1, 256, 0, stream>>>(g1w1, fc_w, fc_b, wcTl, bc, gcur);
        k_convfc<<<NN / 32, 256, 0, stream>>>(x, conv_w, conv_b, wcTl, bc, A);
        k_bin<<<NBIN, 256, 0, stream>>>(ei, gcur, gbin);
        k_sort<<<NGB, 256, 0, stream>>>(gbin, gcur, goff, gsorted);
        // GIN layer 1: atomic-free gather + MLP + layer-2 projection
        k_gagg1<<<NGB, 256, 0, stream>>>(A, goff, gsorted, g1b1, g1w2, g1b2,
                                         g2w1, B);
        // GIN layer 2: atomic-free gather + MLP + readout
        k_gagg2<<<NGB, 256, 0, stream>>>(B, goff, gsorted, g2b1, g2w2, g2b2,
                                         ro_w, ro_b, out);
    } else {
        // --- fallback: fused per-node embed + atomic scatter ---
        k_embed<<<NN / 4, 256, 0, stream>>>(x, conv_w, conv_b, fc_w, fc_b,
                                            g1w1, A);
        hipMemsetAsync(B, 0, (size_t)NN * HID * sizeof(float), stream);
        k_scatter<<<(int)(((long long)NE * HID) / 256), 256, 0, stream>>>(A, ei, B);
        k_mlp1<<<(NN + 255) / 256, 256, 0, stream>>>(A, B, g1b1, g1w2, g1b2,
                                                     g2w1, A);
        hipMemsetAsync(B, 0, (size_t)NN * HID * sizeof(float), stream);
        k_scatter<<<(int)(((long long)NE * HID) / 256), 256, 0, stream>>>(A, ei, B);
        k_final<<<(NN + 255) / 256, 256, 0, stream>>>(A, B, g2b1, g2w2, g2b2,
                                                      ro_w, ro_b, out);
    }
}